// Round 1
// baseline (1235.513 us; speedup 1.0000x reference)
//
#include <hip/hip_runtime.h>
#include <hip/hip_fp16.h>

#define TT 32
#define EN 100
#define DD 128

__device__ __forceinline__ float nan0f(float v) { return (v == v) ? v : 0.f; }

// =====================================================================
// Subnet: per (g,t) polyline encoder.
// h0 = relu(x@W0+b0); c1 = agg0@W1[64:]+b1; h1 = relu(h0@W1[:64]+c1);
// c2 = agg1@W2[64:]+b2; h2 = relu(h1@W2[:64]+c2); out = [agg2, agg2].
// h staged in LDS as f16 transposed [k][n] (thread n owns column n ->
// no cross-thread hazard, no runtime register indexing).
// =====================================================================
__device__ __forceinline__ void reduce_store(const float h[64],
                                             __half (*hls)[256],
                                             float (*red)[64],
                                             int tid, int w)
{
#pragma unroll
    for (int c = 0; c < 64; ++c) hls[c][tid] = __float2half(h[c]);
#pragma unroll
    for (int c = 0; c < 64; ++c) {
        float v = h[c];
#pragma unroll
        for (int m = 1; m <= 32; m <<= 1) v = fmaxf(v, __shfl_xor(v, m, 64));
        red[w][c] = v;   // wave-uniform value; same-address store is benign
    }
    __syncthreads();
}

__global__ __launch_bounds__(256) void subnet_kernel(
    const float* __restrict__ feat,
    const float* __restrict__ W0, const float* __restrict__ B0,
    const float* __restrict__ W1, const float* __restrict__ B1,
    const float* __restrict__ W2, const float* __restrict__ B2,
    float* __restrict__ xout, int N, int e_off, int do_nan0)
{
    const int g = blockIdx.x >> 5;
    const int t = blockIdx.x & 31;
    const int tid = threadIdx.x;
    const int w = tid >> 6;
    const int nwaves = N >> 6;

    __shared__ __half hls[64][256];
    __shared__ float red[4][64];
    __shared__ float cvec[64];

    // ---- load node feature row (16 f32) ----
    const float* xrow = feat + ((size_t)((size_t)g * TT + t) * N + tid) * 16;
    float x[16];
#pragma unroll
    for (int i = 0; i < 4; ++i) {
        float4 v = reinterpret_cast<const float4*>(xrow)[i];
        x[4 * i + 0] = v.x; x[4 * i + 1] = v.y;
        x[4 * i + 2] = v.z; x[4 * i + 3] = v.w;
    }
    if (do_nan0) {
#pragma unroll
        for (int i = 0; i < 16; ++i) x[i] = nan0f(x[i]);
    }

    float h[64];

    // ---- layer 0: h = relu(x @ W0 + b0) ----
#pragma unroll
    for (int c4 = 0; c4 < 16; ++c4) {
        float4 b = reinterpret_cast<const float4*>(B0)[c4];
        h[4 * c4 + 0] = b.x; h[4 * c4 + 1] = b.y;
        h[4 * c4 + 2] = b.z; h[4 * c4 + 3] = b.w;
    }
#pragma unroll
    for (int i = 0; i < 16; ++i) {
        float xi = x[i];
#pragma unroll
        for (int c4 = 0; c4 < 16; ++c4) {
            float4 wv = reinterpret_cast<const float4*>(W0)[i * 16 + c4];
            h[4 * c4 + 0] = fmaf(xi, wv.x, h[4 * c4 + 0]);
            h[4 * c4 + 1] = fmaf(xi, wv.y, h[4 * c4 + 1]);
            h[4 * c4 + 2] = fmaf(xi, wv.z, h[4 * c4 + 2]);
            h[4 * c4 + 3] = fmaf(xi, wv.w, h[4 * c4 + 3]);
        }
    }
#pragma unroll
    for (int c = 0; c < 64; ++c) h[c] = fmaxf(h[c], 0.f);

    // ---- layers 1 and 2 ----
    const float* Wn[2] = { W1, W2 };
    const float* Bn[2] = { B1, B2 };
#pragma unroll 1
    for (int layer = 0; layer < 2; ++layer) {
        const float* Wl = Wn[layer];
        const float* Bl = Bn[layer];

        reduce_store(h, hls, red, tid, w);
        if (tid < 64) {
            float a = red[0][tid];
            for (int ww = 1; ww < nwaves; ++ww) a = fmaxf(a, red[ww][tid]);
            float s = Bl[tid];
#pragma unroll 8
            for (int i = 0; i < 64; ++i)
                s = fmaf(__shfl(a, i, 64), Wl[(size_t)(64 + i) * 64 + tid], s);
            cvec[tid] = s;
        }
        __syncthreads();

#pragma unroll
        for (int c4 = 0; c4 < 16; ++c4) {
            float4 cv = reinterpret_cast<const float4*>(cvec)[c4];
            h[4 * c4 + 0] = cv.x; h[4 * c4 + 1] = cv.y;
            h[4 * c4 + 2] = cv.z; h[4 * c4 + 3] = cv.w;
        }
#pragma unroll 4
        for (int i = 0; i < 64; ++i) {
            float hi = __half2float(hls[i][tid]);
#pragma unroll
            for (int c4 = 0; c4 < 16; ++c4) {
                float4 wv = reinterpret_cast<const float4*>(Wl)[i * 16 + c4];
                h[4 * c4 + 0] = fmaf(hi, wv.x, h[4 * c4 + 0]);
                h[4 * c4 + 1] = fmaf(hi, wv.y, h[4 * c4 + 1]);
                h[4 * c4 + 2] = fmaf(hi, wv.z, h[4 * c4 + 2]);
                h[4 * c4 + 3] = fmaf(hi, wv.w, h[4 * c4 + 3]);
            }
        }
#pragma unroll
        for (int c = 0; c < 64; ++c) h[c] = fmaxf(h[c], 0.f);
        __syncthreads();   // red/cvec reuse protection before next layer
    }

    // ---- final: agg2 duplicated into both halves of the D=128 feature ----
    reduce_store(h, hls, red, tid, w);
    if (tid < 64) {
        float a = red[0][tid];
        for (int ww = 1; ww < nwaves; ++ww) a = fmaxf(a, red[ww][tid]);
        size_t base = ((size_t)t * EN + (e_off + g)) * DD;
        xout[base + tid] = a;
        xout[base + 64 + tid] = a;
    }
}

// =====================================================================
// Generic f32 GEMM: Out[slice] = act( X[slice] @ W[slice] + Bias[slice] )
// rows multiple of 4, K = 128, cols <= 128. Thread (r,c) does c and c+64.
// =====================================================================
__global__ __launch_bounds__(256) void gemm_rt(
    const float* __restrict__ X, long long sX,
    const float* __restrict__ W, long long sW,
    const float* __restrict__ Bias, long long sB,
    float* __restrict__ Out, long long sO,
    int rows, int cols, int act)
{
    const int K = 128;
    const int slice = blockIdx.y;
    X += (size_t)slice * sX;
    W += (size_t)slice * sW;
    Out += (size_t)slice * sO;
    const float* Bp = Bias ? (Bias + (size_t)slice * sB) : nullptr;

    __shared__ float xs[4][128];
    const int tid = threadIdx.x;
    const int r0 = blockIdx.x * 4;
    for (int i = tid; i < 4 * K; i += 256) {
        int r = i >> 7, kk = i & 127;
        xs[r][kk] = X[(size_t)(r0 + r) * K + kk];
    }
    __syncthreads();

    const int rl = tid >> 6;
    const int c = tid & 63;
    const int r = r0 + rl;
    float acc0 = 0.f, acc1 = 0.f;
    const bool two = (c + 64) < cols;
    const float* Wc = W + c;
#pragma unroll 4
    for (int k = 0; k < K; ++k) {
        float xv = xs[rl][k];
        acc0 = fmaf(xv, Wc[(size_t)k * cols], acc0);
        if (two) acc1 = fmaf(xv, Wc[(size_t)k * cols + 64], acc1);
    }
    if (c < cols) {
        float v0 = acc0 + (Bp ? Bp[c] : 0.f);
        if (act) v0 = tanhf(v0);
        Out[(size_t)r * cols + c] = v0;
    }
    if (two) {
        float v1 = acc1 + (Bp ? Bp[c + 64] : 0.f);
        if (act) v1 = tanhf(v1);
        Out[(size_t)r * cols + c + 64] = v1;
    }
}

// =====================================================================
// Attention: per (t, 25-row chunk). K in LDS (stride 129 -> conflict-free),
// wave-local softmax over 100 scores, V streamed from global (L1-hot).
// =====================================================================
__global__ __launch_bounds__(256) void attn_kernel(
    const float* __restrict__ qb, const float* __restrict__ kb,
    const float* __restrict__ vb, float* __restrict__ ob)
{
    const int t = blockIdx.y;
    const int rblk = blockIdx.x;
    const int tid = threadIdx.x, w = tid >> 6, lane = tid & 63;

    __shared__ float ks[EN * 129];
    __shared__ float qs[4][128];
    __shared__ float ps[4][128];

    const float* kt = kb + (size_t)t * EN * DD;
    for (int i = tid; i < EN * DD; i += 256) {
        int f = i >> 7, d = i & 127;
        ks[f * 129 + d] = kt[i];
    }
    __syncthreads();

    const float scale = 0.088388347648318447f;   // 1/sqrt(128)
    const float* vt = vb + (size_t)t * EN * DD;
    const int f2 = lane + 64;
    const bool has2 = f2 < EN;
    const float* krow0 = &ks[lane * 129];
    const float* krow1 = &ks[(has2 ? f2 : lane) * 129];

    for (int e = rblk * 25 + w; e < rblk * 25 + 25; e += 4) {
        const float* qrow = qb + ((size_t)t * EN + e) * DD;
        float q0 = qrow[lane], q1 = qrow[lane + 64];
        qs[w][lane] = q0; qs[w][lane + 64] = q1;

        float s0 = 0.f, s1 = 0.f;
#pragma unroll 4
        for (int d = 0; d < DD; ++d) {
            float qd = qs[w][d];
            s0 = fmaf(qd, krow0[d], s0);
            s1 = fmaf(qd, krow1[d], s1);
        }
        s0 *= scale; s1 *= scale;

        float m = has2 ? fmaxf(s0, s1) : s0;
#pragma unroll
        for (int mm = 1; mm <= 32; mm <<= 1) m = fmaxf(m, __shfl_xor(m, mm, 64));
        float p0 = __expf(s0 - m);
        float p1 = has2 ? __expf(s1 - m) : 0.f;
        float l = p0 + p1;
#pragma unroll
        for (int mm = 1; mm <= 32; mm <<= 1) l += __shfl_xor(l, mm, 64);
        float inv = 1.f / l;
        ps[w][lane] = p0 * inv;
        if (has2) ps[w][f2] = p1 * inv;

        float o0 = 0.f, o1 = 0.f;
#pragma unroll 4
        for (int f = 0; f < EN; ++f) {
            float pf = ps[w][f];
            o0 = fmaf(pf, vt[(size_t)f * DD + lane], o0);
            o1 = fmaf(pf, vt[(size_t)f * DD + lane + 64], o1);
        }
        float* orow = ob + ((size_t)t * EN + e) * DD;
        orow[lane] = o0;
        orow[lane + 64] = o1;
    }
}

// =====================================================================
extern "C" void kernel_launch(void* const* d_in, const int* in_sizes, int n_in,
                              void* d_out, int out_size, void* d_ws, size_t ws_size,
                              hipStream_t stream)
{
    const float* agent_feature = (const float*)d_in[2];
    const float* map_feature   = (const float*)d_in[3];
    const float* obj_feature   = (const float*)d_in[6];
    const float* aW0 = (const float*)d_in[7];  const float* aB0 = (const float*)d_in[8];
    const float* aW1 = (const float*)d_in[9];  const float* aB1 = (const float*)d_in[10];
    const float* aW2 = (const float*)d_in[11]; const float* aB2 = (const float*)d_in[12];
    const float* mW0 = (const float*)d_in[13]; const float* mB0 = (const float*)d_in[14];
    const float* mW1 = (const float*)d_in[15]; const float* mB1 = (const float*)d_in[16];
    const float* mW2 = (const float*)d_in[17]; const float* mB2 = (const float*)d_in[18];
    const float* oW0 = (const float*)d_in[19]; const float* oB0 = (const float*)d_in[20];
    const float* oW1 = (const float*)d_in[21]; const float* oB1 = (const float*)d_in[22];
    const float* oW2 = (const float*)d_in[23]; const float* oB2 = (const float*)d_in[24];
    const float* Wq = (const float*)d_in[25];
    const float* Wk = (const float*)d_in[26];
    const float* Wv = (const float*)d_in[27];
    const float* mlpW1 = (const float*)d_in[28]; const float* mlpB1 = (const float*)d_in[29];
    const float* mlpW2 = (const float*)d_in[30]; const float* mlpB2 = (const float*)d_in[31];

    // ws layout (f32): xbuf | qbuf | kbuf | vbuf | obuf ; hdn aliases xbuf..vbuf
    float* xbuf = (float*)d_ws;            // 409600  [T,E,128]
    float* qbuf = xbuf + 409600;           // 409600
    float* kbuf = qbuf + 409600;           // 409600
    float* vbuf = kbuf + 409600;           // 409600
    float* obuf = vbuf + 409600;           // 409600
    float* hdn  = xbuf;                    // 4*409600, reuses x/q/k/v (dead by then)
    float* outp = (float*)d_out;

    // polyline subgraphs -> x [T, E=100, 128]
    subnet_kernel<<<dim3(4 * 32), 256, 0, stream>>>(
        agent_feature, aW0, aB0, aW1, aB1, aW2, aB2, xbuf, 256, 0, 1);
    subnet_kernel<<<dim3(64 * 32), 256, 0, stream>>>(
        map_feature, mW0, mB0, mW1, mB1, mW2, mB2, xbuf, 256, 4, 0);
    subnet_kernel<<<dim3(32 * 32), 128, 0, stream>>>(
        obj_feature, oW0, oB0, oW1, oB1, oW2, oB2, xbuf, 128, 68, 0);

    // q, k, v
    gemm_rt<<<dim3(800, 1), 256, 0, stream>>>(xbuf, 0, Wq, 0, nullptr, 0, qbuf, 0, 3200, 128, 0);
    gemm_rt<<<dim3(800, 1), 256, 0, stream>>>(xbuf, 0, Wk, 0, nullptr, 0, kbuf, 0, 3200, 128, 0);
    gemm_rt<<<dim3(800, 1), 256, 0, stream>>>(xbuf, 0, Wv, 0, nullptr, 0, vbuf, 0, 3200, 128, 0);

    // softmax(q k^T / sqrt(D)) v
    attn_kernel<<<dim3(4, 32), 256, 0, stream>>>(qbuf, kbuf, vbuf, obuf);

    // per-agent MLP head
    gemm_rt<<<dim3(800, 4), 256, 0, stream>>>(obuf, 0, mlpW1, 16384, mlpB1, 128,
                                              hdn, 409600, 3200, 128, 1);
    gemm_rt<<<dim3(800, 4), 256, 0, stream>>>(hdn, 409600, mlpW2, 7680, mlpB2, 60,
                                              outp, 192000, 3200, 60, 0);
}

// Round 2
// 294.495 us; speedup vs baseline: 4.1954x; 4.1954x over previous
//
#include <hip/hip_runtime.h>
#include <hip/hip_fp16.h>

#define TT 32
#define EN 100
#define DD 128

typedef _Float16 half4 __attribute__((ext_vector_type(4)));
typedef float f32x4 __attribute__((ext_vector_type(4)));

#define MFMA16(a, b, c) __builtin_amdgcn_mfma_f32_16x16x16f16((a), (b), (c), 0, 0, 0)

__device__ __forceinline__ float nan0f(float v) { return (v == v) ? v : 0.f; }

// =====================================================================
// MFMA subnet: 1 block = 1 (g,t) polyline, 4 waves, wave owns 16*MT rows.
// H staged in LDS f16, row stride 144 B, XOR swizzle addr ^= 16*((r>>2)&3)
//   -> conflict-free b16 C-writes, ~optimal b64 A-frag reads.
// B-fragments straight from global W (L1-hot). agg via register max +
// shfl_xor; cvec (= agg @ W[64:] + b, the folded concat term) in f32.
// =====================================================================
template<int MT, int DO_NAN0>
__global__ __launch_bounds__(256, 4) void subnet_mfma(
    const float* __restrict__ feat,
    const float* __restrict__ W0, const float* __restrict__ B0,
    const float* __restrict__ W1, const float* __restrict__ B1,
    const float* __restrict__ W2, const float* __restrict__ B2,
    float* __restrict__ xout, int e_off)
{
    constexpr int N = MT * 64;
    const int g = blockIdx.x >> 5;
    const int t = blockIdx.x & 31;
    const int tid = threadIdx.x;
    const int w = tid >> 6;
    const int lane = tid & 63;
    const int ml = lane & 15;
    const int gq = lane >> 4;
    const int rowbase = w * (16 * MT);

    __shared__ __attribute__((aligned(16))) unsigned char Hs[N * 144];
    __shared__ float red[4][64];
    __shared__ float cvec[64];

    const int Xw = gq << 4;           // write swizzle (const per lane)
    const int Xr = (ml >> 2) << 4;    // read swizzle (consistent: r&12 == ml bits)

    f32x4 acc[MT][4];

    // relu + per-col max + (optional) f16 store to LDS + cross-wave red
    auto epilogue = [&](bool store) {
#pragma unroll
        for (int nt = 0; nt < 4; ++nt) {
            float am = 0.f;
#pragma unroll
            for (int mt = 0; mt < MT; ++mt) {
                f32x4 v = acc[mt][nt];
                v.x = fmaxf(v.x, 0.f); v.y = fmaxf(v.y, 0.f);
                v.z = fmaxf(v.z, 0.f); v.w = fmaxf(v.w, 0.f);
                am = fmaxf(am, fmaxf(fmaxf(v.x, v.y), fmaxf(v.z, v.w)));
                if (store) {
                    const int a0 = (rowbase + mt * 16 + gq * 4) * 144 + (nt * 16 + ml) * 2;
                    *(_Float16*)(Hs + ((a0      ) ^ Xw)) = (_Float16)v.x;
                    *(_Float16*)(Hs + ((a0 + 144) ^ Xw)) = (_Float16)v.y;
                    *(_Float16*)(Hs + ((a0 + 288) ^ Xw)) = (_Float16)v.z;
                    *(_Float16*)(Hs + ((a0 + 432) ^ Xw)) = (_Float16)v.w;
                }
            }
            am = fmaxf(am, __shfl_xor(am, 16, 64));
            am = fmaxf(am, __shfl_xor(am, 32, 64));
            if (lane < 16) red[w][nt * 16 + lane] = am;
        }
        __syncthreads();
    };

    // cvec[n] = Bn[n] + sum_k agg[k] * Wn[(64+k)*64 + n]   (f32 path)
    auto make_cvec = [&](const float* __restrict__ Wn, const float* __restrict__ Bn) {
        if (w == 0) {
            float a = fmaxf(fmaxf(red[0][lane], red[1][lane]),
                            fmaxf(red[2][lane], red[3][lane]));
            float s = Bn[lane];
#pragma unroll 8
            for (int k = 0; k < 64; ++k)
                s = fmaf(__shfl(a, k, 64), Wn[(size_t)(64 + k) * 64 + lane], s);
            cvec[lane] = s;
        }
        __syncthreads();
    };

    // ---------------- layer 0: H0 = relu(X @ W0 + b0) ----------------
    {
#pragma unroll
        for (int nt = 0; nt < 4; ++nt) {
            float b = B0[nt * 16 + ml];
#pragma unroll
            for (int mt = 0; mt < MT; ++mt) acc[mt][nt] = f32x4{b, b, b, b};
        }
        half4 bf[4];
#pragma unroll
        for (int nt = 0; nt < 4; ++nt) {
            const float* wp = W0 + (gq * 4) * 64 + nt * 16 + ml;
            bf[nt] = half4{(_Float16)wp[0], (_Float16)wp[64],
                           (_Float16)wp[128], (_Float16)wp[192]};
        }
        const float* xb = feat + (size_t)(g * TT + t) * N * 16;
#pragma unroll
        for (int mt = 0; mt < MT; ++mt) {
            float4 xv = *reinterpret_cast<const float4*>(
                xb + (size_t)(rowbase + mt * 16 + ml) * 16 + gq * 4);
            if (DO_NAN0) {
                xv.x = nan0f(xv.x); xv.y = nan0f(xv.y);
                xv.z = nan0f(xv.z); xv.w = nan0f(xv.w);
            }
            half4 af = half4{(_Float16)xv.x, (_Float16)xv.y,
                             (_Float16)xv.z, (_Float16)xv.w};
#pragma unroll
            for (int nt = 0; nt < 4; ++nt)
                acc[mt][nt] = MFMA16(af, bf[nt], acc[mt][nt]);
        }
    }
    epilogue(true);
    make_cvec(W1, B1);

    // ---------------- layers 1, 2 ----------------
    auto layer = [&](const float* __restrict__ Wl, bool store) {
#pragma unroll
        for (int nt = 0; nt < 4; ++nt) {
            float cv = cvec[nt * 16 + ml];
#pragma unroll
            for (int mt = 0; mt < MT; ++mt) acc[mt][nt] = f32x4{cv, cv, cv, cv};
        }
#pragma unroll
        for (int kt = 0; kt < 4; ++kt) {
            half4 bf[4];
#pragma unroll
            for (int nt = 0; nt < 4; ++nt) {
                const float* wp = Wl + (size_t)(kt * 16 + gq * 4) * 64 + nt * 16 + ml;
                bf[nt] = half4{(_Float16)wp[0], (_Float16)wp[64],
                               (_Float16)wp[128], (_Float16)wp[192]};
            }
#pragma unroll
            for (int mt = 0; mt < MT; ++mt) {
                const int addr = (((rowbase + mt * 16 + ml) * 144) + kt * 32 + gq * 8) ^ Xr;
                half4 af = *reinterpret_cast<const half4*>(Hs + addr);
#pragma unroll
                for (int nt = 0; nt < 4; ++nt)
                    acc[mt][nt] = MFMA16(af, bf[nt], acc[mt][nt]);
            }
        }
        epilogue(store);
    };

    layer(W1, true);
    make_cvec(W2, B2);
    layer(W2, false);   // H2 only feeds agg -> no LDS store

    // ---------------- output: agg2 duplicated ----------------
    if (w == 0) {
        float a = fmaxf(fmaxf(red[0][lane], red[1][lane]),
                        fmaxf(red[2][lane], red[3][lane]));
        size_t base = ((size_t)t * EN + (e_off + g)) * DD;
        xout[base + lane] = a;
        xout[base + 64 + lane] = a;
    }
}

// =====================================================================
// Generic f32 GEMM: Out[slice] = act( X[slice] @ W[slice] + Bias[slice] )
// =====================================================================
__global__ __launch_bounds__(256) void gemm_rt(
    const float* __restrict__ X, long long sX,
    const float* __restrict__ W, long long sW,
    const float* __restrict__ Bias, long long sB,
    float* __restrict__ Out, long long sO,
    int rows, int cols, int act)
{
    const int K = 128;
    const int slice = blockIdx.y;
    X += (size_t)slice * sX;
    W += (size_t)slice * sW;
    Out += (size_t)slice * sO;
    const float* Bp = Bias ? (Bias + (size_t)slice * sB) : nullptr;

    __shared__ float xs[4][128];
    const int tid = threadIdx.x;
    const int r0 = blockIdx.x * 4;
    for (int i = tid; i < 4 * K; i += 256) {
        int r = i >> 7, kk = i & 127;
        xs[r][kk] = X[(size_t)(r0 + r) * K + kk];
    }
    __syncthreads();

    const int rl = tid >> 6;
    const int c = tid & 63;
    const int r = r0 + rl;
    float acc0 = 0.f, acc1 = 0.f;
    const bool two = (c + 64) < cols;
    const float* Wc = W + c;
#pragma unroll 4
    for (int k = 0; k < K; ++k) {
        float xv = xs[rl][k];
        acc0 = fmaf(xv, Wc[(size_t)k * cols], acc0);
        if (two) acc1 = fmaf(xv, Wc[(size_t)k * cols + 64], acc1);
    }
    if (c < cols) {
        float v0 = acc0 + (Bp ? Bp[c] : 0.f);
        if (act) v0 = tanhf(v0);
        Out[(size_t)r * cols + c] = v0;
    }
    if (two) {
        float v1 = acc1 + (Bp ? Bp[c + 64] : 0.f);
        if (act) v1 = tanhf(v1);
        Out[(size_t)r * cols + c + 64] = v1;
    }
}

// =====================================================================
// QKV fused: blockIdx.y selects {Wq,Wk,Wv} -> {q,k,v}. rows=3200 cols=128.
// =====================================================================
__global__ __launch_bounds__(256) void gemm_qkv(
    const float* __restrict__ X,
    const float* __restrict__ Wq, const float* __restrict__ Wk, const float* __restrict__ Wv,
    float* __restrict__ qb, float* __restrict__ kb, float* __restrict__ vb)
{
    const float* W; float* Out;
    if (blockIdx.y == 0)      { W = Wq; Out = qb; }
    else if (blockIdx.y == 1) { W = Wk; Out = kb; }
    else                      { W = Wv; Out = vb; }

    __shared__ float xs[4][128];
    const int tid = threadIdx.x;
    const int r0 = blockIdx.x * 4;
    for (int i = tid; i < 512; i += 256)
        xs[i >> 7][i & 127] = X[(size_t)r0 * 128 + i];
    __syncthreads();

    const int rl = tid >> 6, c = tid & 63;
    float acc0 = 0.f, acc1 = 0.f;
    const float* Wc = W + c;
#pragma unroll 4
    for (int k = 0; k < 128; ++k) {
        float xv = xs[rl][k];
        acc0 = fmaf(xv, Wc[k * 128], acc0);
        acc1 = fmaf(xv, Wc[k * 128 + 64], acc1);
    }
    float* orow = Out + (size_t)(r0 + rl) * 128 + c;
    orow[0] = acc0;
    orow[64] = acc1;
}

// =====================================================================
// Attention: per (t, 25-row chunk). K in LDS stride 129, wave softmax.
// =====================================================================
__global__ __launch_bounds__(256) void attn_kernel(
    const float* __restrict__ qb, const float* __restrict__ kb,
    const float* __restrict__ vb, float* __restrict__ ob)
{
    const int t = blockIdx.y;
    const int rblk = blockIdx.x;
    const int tid = threadIdx.x, w = tid >> 6, lane = tid & 63;

    __shared__ float ks[EN * 129];
    __shared__ float qs[4][128];
    __shared__ float ps[4][128];

    const float* kt = kb + (size_t)t * EN * DD;
    for (int i = tid; i < EN * DD; i += 256) {
        int f = i >> 7, d = i & 127;
        ks[f * 129 + d] = kt[i];
    }
    __syncthreads();

    const float scale = 0.088388347648318447f;   // 1/sqrt(128)
    const float* vt = vb + (size_t)t * EN * DD;
    const int f2 = lane + 64;
    const bool has2 = f2 < EN;
    const float* krow0 = &ks[lane * 129];
    const float* krow1 = &ks[(has2 ? f2 : lane) * 129];

    for (int e = rblk * 25 + w; e < rblk * 25 + 25; e += 4) {
        const float* qrow = qb + ((size_t)t * EN + e) * DD;
        float q0 = qrow[lane], q1 = qrow[lane + 64];
        qs[w][lane] = q0; qs[w][lane + 64] = q1;

        float s0 = 0.f, s1 = 0.f;
#pragma unroll 4
        for (int d = 0; d < DD; ++d) {
            float qd = qs[w][d];
            s0 = fmaf(qd, krow0[d], s0);
            s1 = fmaf(qd, krow1[d], s1);
        }
        s0 *= scale; s1 *= scale;

        float m = has2 ? fmaxf(s0, s1) : s0;
#pragma unroll
        for (int mm = 1; mm <= 32; mm <<= 1) m = fmaxf(m, __shfl_xor(m, mm, 64));
        float p0 = __expf(s0 - m);
        float p1 = has2 ? __expf(s1 - m) : 0.f;
        float l = p0 + p1;
#pragma unroll
        for (int mm = 1; mm <= 32; mm <<= 1) l += __shfl_xor(l, mm, 64);
        float inv = 1.f / l;
        ps[w][lane] = p0 * inv;
        if (has2) ps[w][f2] = p1 * inv;

        float o0 = 0.f, o1 = 0.f;
#pragma unroll 4
        for (int f = 0; f < EN; ++f) {
            float pf = ps[w][f];
            o0 = fmaf(pf, vt[(size_t)f * DD + lane], o0);
            o1 = fmaf(pf, vt[(size_t)f * DD + lane + 64], o1);
        }
        float* orow = ob + ((size_t)t * EN + e) * DD;
        orow[lane] = o0;
        orow[lane + 64] = o1;
    }
}

// =====================================================================
extern "C" void kernel_launch(void* const* d_in, const int* in_sizes, int n_in,
                              void* d_out, int out_size, void* d_ws, size_t ws_size,
                              hipStream_t stream)
{
    const float* agent_feature = (const float*)d_in[2];
    const float* map_feature   = (const float*)d_in[3];
    const float* obj_feature   = (const float*)d_in[6];
    const float* aW0 = (const float*)d_in[7];  const float* aB0 = (const float*)d_in[8];
    const float* aW1 = (const float*)d_in[9];  const float* aB1 = (const float*)d_in[10];
    const float* aW2 = (const float*)d_in[11]; const float* aB2 = (const float*)d_in[12];
    const float* mW0 = (const float*)d_in[13]; const float* mB0 = (const float*)d_in[14];
    const float* mW1 = (const float*)d_in[15]; const float* mB1 = (const float*)d_in[16];
    const float* mW2 = (const float*)d_in[17]; const float* mB2 = (const float*)d_in[18];
    const float* oW0 = (const float*)d_in[19]; const float* oB0 = (const float*)d_in[20];
    const float* oW1 = (const float*)d_in[21]; const float* oB1 = (const float*)d_in[22];
    const float* oW2 = (const float*)d_in[23]; const float* oB2 = (const float*)d_in[24];
    const float* Wq = (const float*)d_in[25];
    const float* Wk = (const float*)d_in[26];
    const float* Wv = (const float*)d_in[27];
    const float* mlpW1 = (const float*)d_in[28]; const float* mlpB1 = (const float*)d_in[29];
    const float* mlpW2 = (const float*)d_in[30]; const float* mlpB2 = (const float*)d_in[31];

    float* xbuf = (float*)d_ws;            // [T,E,128]
    float* qbuf = xbuf + 409600;
    float* kbuf = qbuf + 409600;
    float* vbuf = kbuf + 409600;
    float* obuf = vbuf + 409600;
    float* hdn  = xbuf;                    // 4 slices, reuses x/q/k/v (dead by then)
    float* outp = (float*)d_out;

    // polyline subgraphs -> x [T, E=100, 128]
    subnet_mfma<4, 1><<<dim3(4 * 32), 256, 0, stream>>>(
        agent_feature, aW0, aB0, aW1, aB1, aW2, aB2, xbuf, 0);
    subnet_mfma<4, 0><<<dim3(64 * 32), 256, 0, stream>>>(
        map_feature, mW0, mB0, mW1, mB1, mW2, mB2, xbuf, 4);
    subnet_mfma<2, 0><<<dim3(32 * 32), 256, 0, stream>>>(
        obj_feature, oW0, oB0, oW1, oB1, oW2, oB2, xbuf, 68);

    // q, k, v (fused launch)
    gemm_qkv<<<dim3(800, 3), 256, 0, stream>>>(xbuf, Wq, Wk, Wv, qbuf, kbuf, vbuf);

    // softmax(q k^T / sqrt(D)) v
    attn_kernel<<<dim3(4, 32), 256, 0, stream>>>(qbuf, kbuf, vbuf, obuf);

    // per-agent MLP head
    gemm_rt<<<dim3(800, 4), 256, 0, stream>>>(obuf, 0, mlpW1, 16384, mlpB1, 128,
                                              hdn, 409600, 3200, 128, 1);
    gemm_rt<<<dim3(800, 4), 256, 0, stream>>>(hdn, 409600, mlpW2, 7680, mlpB2, 60,
                                              outp, 192000, 3200, 60, 0);
}

// Round 3
// 203.943 us; speedup vs baseline: 6.0581x; 1.4440x over previous
//
#include <hip/hip_runtime.h>
#include <hip/hip_fp16.h>

#define TT 32
#define EN 100
#define DD 128

typedef _Float16 half4 __attribute__((ext_vector_type(4)));
typedef float f32x4 __attribute__((ext_vector_type(4)));

#define MFMA16(a, b, c) __builtin_amdgcn_mfma_f32_16x16x16f16((a), (b), (c), 0, 0, 0)

__device__ __forceinline__ float nan0f(float v) { return (v == v) ? v : 0.f; }

// 2-panel (64-col) f16 tile, row stride 136B, XOR swizzle on byte bits 4-5.
// ps = panel size in bytes (= rows*136).
__device__ __forceinline__ int ldsoff(int ps, int row, int col) {
    int b = (col >> 6) * ps + row * 136 + ((col & 63) << 1);
    return b ^ ((row & 12) << 2);
}

// =====================================================================
// MFMA subnet (unchanged, verified): 1 block = 1 (g,t) polyline.
// =====================================================================
template<int MT, int DO_NAN0>
__global__ __launch_bounds__(256, 4) void subnet_mfma(
    const float* __restrict__ feat,
    const float* __restrict__ W0, const float* __restrict__ B0,
    const float* __restrict__ W1, const float* __restrict__ B1,
    const float* __restrict__ W2, const float* __restrict__ B2,
    float* __restrict__ xout, int e_off)
{
    constexpr int N = MT * 64;
    const int g = blockIdx.x >> 5;
    const int t = blockIdx.x & 31;
    const int tid = threadIdx.x;
    const int w = tid >> 6;
    const int lane = tid & 63;
    const int ml = lane & 15;
    const int gq = lane >> 4;
    const int rowbase = w * (16 * MT);

    __shared__ __attribute__((aligned(16))) unsigned char Hs[N * 144];
    __shared__ float red[4][64];
    __shared__ float cvec[64];

    const int Xw = gq << 4;
    const int Xr = (ml >> 2) << 4;

    f32x4 acc[MT][4];

    auto epilogue = [&](bool store) {
#pragma unroll
        for (int nt = 0; nt < 4; ++nt) {
            float am = 0.f;
#pragma unroll
            for (int mt = 0; mt < MT; ++mt) {
                f32x4 v = acc[mt][nt];
                v.x = fmaxf(v.x, 0.f); v.y = fmaxf(v.y, 0.f);
                v.z = fmaxf(v.z, 0.f); v.w = fmaxf(v.w, 0.f);
                am = fmaxf(am, fmaxf(fmaxf(v.x, v.y), fmaxf(v.z, v.w)));
                if (store) {
                    const int a0 = (rowbase + mt * 16 + gq * 4) * 144 + (nt * 16 + ml) * 2;
                    *(_Float16*)(Hs + ((a0      ) ^ Xw)) = (_Float16)v.x;
                    *(_Float16*)(Hs + ((a0 + 144) ^ Xw)) = (_Float16)v.y;
                    *(_Float16*)(Hs + ((a0 + 288) ^ Xw)) = (_Float16)v.z;
                    *(_Float16*)(Hs + ((a0 + 432) ^ Xw)) = (_Float16)v.w;
                }
            }
            am = fmaxf(am, __shfl_xor(am, 16, 64));
            am = fmaxf(am, __shfl_xor(am, 32, 64));
            if (lane < 16) red[w][nt * 16 + lane] = am;
        }
        __syncthreads();
    };

    auto make_cvec = [&](const float* __restrict__ Wn, const float* __restrict__ Bn) {
        if (w == 0) {
            float a = fmaxf(fmaxf(red[0][lane], red[1][lane]),
                            fmaxf(red[2][lane], red[3][lane]));
            float s = Bn[lane];
#pragma unroll 8
            for (int k = 0; k < 64; ++k)
                s = fmaf(__shfl(a, k, 64), Wn[(size_t)(64 + k) * 64 + lane], s);
            cvec[lane] = s;
        }
        __syncthreads();
    };

    {
#pragma unroll
        for (int nt = 0; nt < 4; ++nt) {
            float b = B0[nt * 16 + ml];
#pragma unroll
            for (int mt = 0; mt < MT; ++mt) acc[mt][nt] = f32x4{b, b, b, b};
        }
        half4 bf[4];
#pragma unroll
        for (int nt = 0; nt < 4; ++nt) {
            const float* wp = W0 + (gq * 4) * 64 + nt * 16 + ml;
            bf[nt] = half4{(_Float16)wp[0], (_Float16)wp[64],
                           (_Float16)wp[128], (_Float16)wp[192]};
        }
        const float* xb = feat + (size_t)(g * TT + t) * N * 16;
#pragma unroll
        for (int mt = 0; mt < MT; ++mt) {
            float4 xv = *reinterpret_cast<const float4*>(
                xb + (size_t)(rowbase + mt * 16 + ml) * 16 + gq * 4);
            if (DO_NAN0) {
                xv.x = nan0f(xv.x); xv.y = nan0f(xv.y);
                xv.z = nan0f(xv.z); xv.w = nan0f(xv.w);
            }
            half4 af = half4{(_Float16)xv.x, (_Float16)xv.y,
                             (_Float16)xv.z, (_Float16)xv.w};
#pragma unroll
            for (int nt = 0; nt < 4; ++nt)
                acc[mt][nt] = MFMA16(af, bf[nt], acc[mt][nt]);
        }
    }
    epilogue(true);
    make_cvec(W1, B1);

    auto layer = [&](const float* __restrict__ Wl, bool store) {
#pragma unroll
        for (int nt = 0; nt < 4; ++nt) {
            float cv = cvec[nt * 16 + ml];
#pragma unroll
            for (int mt = 0; mt < MT; ++mt) acc[mt][nt] = f32x4{cv, cv, cv, cv};
        }
#pragma unroll
        for (int kt = 0; kt < 4; ++kt) {
            half4 bf[4];
#pragma unroll
            for (int nt = 0; nt < 4; ++nt) {
                const float* wp = Wl + (size_t)(kt * 16 + gq * 4) * 64 + nt * 16 + ml;
                bf[nt] = half4{(_Float16)wp[0], (_Float16)wp[64],
                               (_Float16)wp[128], (_Float16)wp[192]};
            }
#pragma unroll
            for (int mt = 0; mt < MT; ++mt) {
                const int addr = (((rowbase + mt * 16 + ml) * 144) + kt * 32 + gq * 8) ^ Xr;
                half4 af = *reinterpret_cast<const half4*>(Hs + addr);
#pragma unroll
                for (int nt = 0; nt < 4; ++nt)
                    acc[mt][nt] = MFMA16(af, bf[nt], acc[mt][nt]);
            }
        }
        epilogue(store);
    };

    layer(W1, true);
    make_cvec(W2, B2);
    layer(W2, false);

    if (w == 0) {
        float a = fmaxf(fmaxf(red[0][lane], red[1][lane]),
                        fmaxf(red[2][lane], red[3][lane]));
        size_t base = ((size_t)t * EN + (e_off + g)) * DD;
        xout[base + lane] = a;
        xout[base + 64 + lane] = a;
    }
}

// =====================================================================
// QKV per t: X staged f16 (rows padded to 112 with zeros), W staged f16,
// Q/K/V written f16 [t][112][128] to workspace (pad rows become zeros).
// =====================================================================
#define PSX 15232          // 112*136
#define WSO 30464          // X region size (2 panels)
#define PSW 17408          // 128*136

__global__ __launch_bounds__(256) void qkv_kernel(
    const float* __restrict__ xbuf,
    const float* __restrict__ Wq, const float* __restrict__ Wk, const float* __restrict__ Wv,
    _Float16* __restrict__ qh, _Float16* __restrict__ kh, _Float16* __restrict__ vh)
{
    const int t = blockIdx.x;
    const int tid = threadIdx.x;
    const int w = tid >> 6, lane = tid & 63, ml = lane & 15, gq = lane >> 4;

    __shared__ __attribute__((aligned(16))) unsigned char sm[WSO + 2 * PSW];

    // stage X[t] -> f16 (zero rows 100..111)
    for (int i = tid; i < 112 * 32; i += 256) {
        int row = i >> 5, c4 = (i & 31) << 2;
        half4 v;
        if (row < EN) {
            float4 f = *reinterpret_cast<const float4*>(xbuf + (size_t)t * EN * DD + row * DD + c4);
            v = half4{(_Float16)f.x, (_Float16)f.y, (_Float16)f.z, (_Float16)f.w};
        } else {
            v = half4{0, 0, 0, 0};
        }
        *(half4*)(sm + ldsoff(PSX, row, c4)) = v;
    }

    for (int tgt = 0; tgt < 3; ++tgt) {
        const float* W = (tgt == 0) ? Wq : (tgt == 1) ? Wk : Wv;
        _Float16* Oh = (tgt == 0) ? qh : (tgt == 1) ? kh : vh;

        // stage W f16 natural [c][d]
        for (int i = tid; i < 128 * 32; i += 256) {
            int row = i >> 5, c4 = (i & 31) << 2;
            float4 f = *reinterpret_cast<const float4*>(W + row * 128 + c4);
            *(half4*)(sm + WSO + ldsoff(PSW, row, c4)) =
                half4{(_Float16)f.x, (_Float16)f.y, (_Float16)f.z, (_Float16)f.w};
        }
        __syncthreads();

#pragma unroll 1
        for (int mi = 0; mi < 2; ++mi) {
            int mt = w + (mi << 2);
            if (mt >= 7) continue;
            half4 xa[8];
#pragma unroll
            for (int kt = 0; kt < 8; ++kt)
                xa[kt] = *(const half4*)(sm + ldsoff(PSX, mt * 16 + ml, kt * 16 + gq * 4));
#pragma unroll
            for (int nt = 0; nt < 8; ++nt) {
                f32x4 acc = {0.f, 0.f, 0.f, 0.f};
                const int col = nt * 16 + ml;
#pragma unroll
                for (int kt = 0; kt < 8; ++kt) {
                    const int r0 = kt * 16 + gq * 4;
                    half4 b = half4{
                        *(const _Float16*)(sm + WSO + ldsoff(PSW, r0 + 0, col)),
                        *(const _Float16*)(sm + WSO + ldsoff(PSW, r0 + 1, col)),
                        *(const _Float16*)(sm + WSO + ldsoff(PSW, r0 + 2, col)),
                        *(const _Float16*)(sm + WSO + ldsoff(PSW, r0 + 3, col))};
                    acc = MFMA16(xa[kt], b, acc);
                }
                _Float16* op = Oh + (size_t)t * 14336 + (mt * 16 + gq * 4) * 128 + col;
                op[0]   = (_Float16)acc.x;
                op[128] = (_Float16)acc.y;
                op[256] = (_Float16)acc.z;
                op[384] = (_Float16)acc.w;
            }
        }
        __syncthreads();
    }
}

// =====================================================================
// Attention per t: K,V staged f16 in LDS; Q A-frags from global;
// in-register softmax; P overwrites the K region; O -> f32 global.
// =====================================================================
#define VSO 30464          // V region offset (after K's 2 panels)

__global__ __launch_bounds__(256) void attn_kernel(
    const _Float16* __restrict__ qh, const _Float16* __restrict__ kh,
    const _Float16* __restrict__ vh, float* __restrict__ obuf)
{
    const int t = blockIdx.x;
    const int tid = threadIdx.x;
    const int w = tid >> 6, lane = tid & 63, ml = lane & 15, gq = lane >> 4;

    __shared__ __attribute__((aligned(16))) unsigned char sm[2 * WSO];

    for (int i = tid; i < 112 * 32; i += 256) {
        int row = i >> 5, c4 = (i & 31) << 2;
        size_t src = (size_t)t * 14336 + row * 128 + c4;
        *(half4*)(sm + ldsoff(PSX, row, c4))       = *(const half4*)(kh + src);
        *(half4*)(sm + VSO + ldsoff(PSX, row, c4)) = *(const half4*)(vh + src);
    }
    __syncthreads();

    const float scale = 0.088388347648318447f;   // 1/sqrt(128)
    half4 pf[2][7];

#pragma unroll 1
    for (int mi = 0; mi < 2; ++mi) {
        int mt = w + (mi << 2);
        if (mt >= 7) continue;
        half4 qa[8];
#pragma unroll
        for (int kt = 0; kt < 8; ++kt)
            qa[kt] = *(const half4*)(qh + (size_t)t * 14336 + (mt * 16 + ml) * 128 + kt * 16 + gq * 4);

        f32x4 sacc[7];
#pragma unroll
        for (int nt = 0; nt < 7; ++nt) {
            f32x4 acc = {0.f, 0.f, 0.f, 0.f};
#pragma unroll
            for (int kt = 0; kt < 8; ++kt) {
                half4 b = *(const half4*)(sm + ldsoff(PSX, nt * 16 + ml, kt * 16 + gq * 4));
                acc = MFMA16(qa[kt], b, acc);
            }
            sacc[nt].x = acc.x * scale; sacc[nt].y = acc.y * scale;
            sacc[nt].z = acc.z * scale; sacc[nt].w = acc.w * scale;
        }
        // softmax over f (cols): per lane holds 4 rows x 7 cols
        float mx[4] = {-3e38f, -3e38f, -3e38f, -3e38f};
#pragma unroll
        for (int nt = 0; nt < 7; ++nt) {
            if (nt < 6 || ml < 4) {
                mx[0] = fmaxf(mx[0], sacc[nt].x); mx[1] = fmaxf(mx[1], sacc[nt].y);
                mx[2] = fmaxf(mx[2], sacc[nt].z); mx[3] = fmaxf(mx[3], sacc[nt].w);
            }
        }
#pragma unroll
        for (int m = 1; m <= 8; m <<= 1) {
#pragma unroll
            for (int i = 0; i < 4; ++i) mx[i] = fmaxf(mx[i], __shfl_xor(mx[i], m, 64));
        }
        float sum[4] = {0.f, 0.f, 0.f, 0.f};
#pragma unroll
        for (int nt = 0; nt < 7; ++nt) {
            bool v = (nt < 6) || (ml < 4);
            float p0 = v ? __expf(sacc[nt].x - mx[0]) : 0.f;
            float p1 = v ? __expf(sacc[nt].y - mx[1]) : 0.f;
            float p2 = v ? __expf(sacc[nt].z - mx[2]) : 0.f;
            float p3 = v ? __expf(sacc[nt].w - mx[3]) : 0.f;
            sum[0] += p0; sum[1] += p1; sum[2] += p2; sum[3] += p3;
            sacc[nt] = f32x4{p0, p1, p2, p3};
        }
#pragma unroll
        for (int m = 1; m <= 8; m <<= 1) {
#pragma unroll
            for (int i = 0; i < 4; ++i) sum[i] += __shfl_xor(sum[i], m, 64);
        }
        float inv[4] = {1.f / sum[0], 1.f / sum[1], 1.f / sum[2], 1.f / sum[3]};
#pragma unroll
        for (int nt = 0; nt < 7; ++nt)
            pf[mi][nt] = half4{(_Float16)(sacc[nt].x * inv[0]), (_Float16)(sacc[nt].y * inv[1]),
                               (_Float16)(sacc[nt].z * inv[2]), (_Float16)(sacc[nt].w * inv[3])};
    }

    __syncthreads();   // all S reads of K done

    // store P into K region ([e][f] layout)
#pragma unroll 1
    for (int mi = 0; mi < 2; ++mi) {
        int mt = w + (mi << 2);
        if (mt >= 7) continue;
        const int row0 = mt * 16 + gq * 4;
#pragma unroll
        for (int nt = 0; nt < 7; ++nt) {
            const int col = nt * 16 + ml;
            *(_Float16*)(sm + ldsoff(PSX, row0 + 0, col)) = pf[mi][nt].x;
            *(_Float16*)(sm + ldsoff(PSX, row0 + 1, col)) = pf[mi][nt].y;
            *(_Float16*)(sm + ldsoff(PSX, row0 + 2, col)) = pf[mi][nt].z;
            *(_Float16*)(sm + ldsoff(PSX, row0 + 3, col)) = pf[mi][nt].w;
        }
    }
    __syncthreads();

    // O = P @ V
#pragma unroll 1
    for (int mi = 0; mi < 2; ++mi) {
        int mt = w + (mi << 2);
        if (mt >= 7) continue;
        half4 pa[7];
#pragma unroll
        for (int kt = 0; kt < 7; ++kt)
            pa[kt] = *(const half4*)(sm + ldsoff(PSX, mt * 16 + ml, kt * 16 + gq * 4));
#pragma unroll
        for (int nt = 0; nt < 8; ++nt) {
            f32x4 acc = {0.f, 0.f, 0.f, 0.f};
            const int col = nt * 16 + ml;
#pragma unroll
            for (int kt = 0; kt < 7; ++kt) {
                const int r0 = kt * 16 + gq * 4;
                half4 b = half4{
                    *(const _Float16*)(sm + VSO + ldsoff(PSX, r0 + 0, col)),
                    *(const _Float16*)(sm + VSO + ldsoff(PSX, r0 + 1, col)),
                    *(const _Float16*)(sm + VSO + ldsoff(PSX, r0 + 2, col)),
                    *(const _Float16*)(sm + VSO + ldsoff(PSX, r0 + 3, col))};
                acc = MFMA16(pa[kt], b, acc);
            }
            const int row0 = mt * 16 + gq * 4;
            float* op = obuf + (size_t)t * EN * DD + row0 * DD + col;
            if (row0 + 0 < EN) op[0]       = acc.x;
            if (row0 + 1 < EN) op[DD]      = acc.y;
            if (row0 + 2 < EN) op[2 * DD]  = acc.z;
            if (row0 + 3 < EN) op[3 * DD]  = acc.w;
        }
    }
}

// =====================================================================
// MLP head: block = (64 rows, agent a). W1 staged f16; hdn via LDS
// (wave-private, no barrier); tanh on acc; masked 60-col epilogue.
// =====================================================================
#define HSO 34816          // after W1's 2 panels
#define PSH 8704           // 64*136

__global__ __launch_bounds__(256) void mlp_kernel(
    const float* __restrict__ obuf,
    const float* __restrict__ W1, const float* __restrict__ B1,
    const float* __restrict__ W2, const float* __restrict__ B2,
    float* __restrict__ out)
{
    const int a = blockIdx.y;
    const int tid = threadIdx.x;
    const int w = tid >> 6, lane = tid & 63, ml = lane & 15, gq = lane >> 4;
    const int rowbase = blockIdx.x * 64 + w * 16;

    __shared__ __attribute__((aligned(16))) unsigned char sm[HSO + PSH * 2];

    // stage W1[a] f16 natural [h_in=128][h_out=128]
    for (int i = tid; i < 128 * 32; i += 256) {
        int row = i >> 5, c4 = (i & 31) << 2;
        float4 f = *reinterpret_cast<const float4*>(W1 + (size_t)a * 16384 + row * 128 + c4);
        *(half4*)(sm + ldsoff(PSW, row, c4)) =
            half4{(_Float16)f.x, (_Float16)f.y, (_Float16)f.z, (_Float16)f.w};
    }
    __syncthreads();

    // layer 1: hdn = tanh(O @ W1 + b1) -> LDS f16 (wave-private rows)
    half4 xa[8];
#pragma unroll
    for (int kt = 0; kt < 8; ++kt) {
        float4 f = *reinterpret_cast<const float4*>(
            obuf + (size_t)(rowbase + ml) * 128 + kt * 16 + gq * 4);
        xa[kt] = half4{(_Float16)f.x, (_Float16)f.y, (_Float16)f.z, (_Float16)f.w};
    }
#pragma unroll
    for (int nt = 0; nt < 8; ++nt) {
        const int col = nt * 16 + ml;
        float bv = B1[a * 128 + col];
        f32x4 acc = {bv, bv, bv, bv};
#pragma unroll
        for (int kt = 0; kt < 8; ++kt) {
            const int r0 = kt * 16 + gq * 4;
            half4 b = half4{
                *(const _Float16*)(sm + ldsoff(PSW, r0 + 0, col)),
                *(const _Float16*)(sm + ldsoff(PSW, r0 + 1, col)),
                *(const _Float16*)(sm + ldsoff(PSW, r0 + 2, col)),
                *(const _Float16*)(sm + ldsoff(PSW, r0 + 3, col))};
            acc = MFMA16(xa[kt], b, acc);
        }
        const int lr0 = w * 16 + gq * 4;
        *(_Float16*)(sm + HSO + ldsoff(PSH, lr0 + 0, col)) = (_Float16)tanhf(acc.x);
        *(_Float16*)(sm + HSO + ldsoff(PSH, lr0 + 1, col)) = (_Float16)tanhf(acc.y);
        *(_Float16*)(sm + HSO + ldsoff(PSH, lr0 + 2, col)) = (_Float16)tanhf(acc.z);
        *(_Float16*)(sm + HSO + ldsoff(PSH, lr0 + 3, col)) = (_Float16)tanhf(acc.w);
    }

    // layer 2: out = hdn @ W2 + b2  (cols 60, wave-private LDS reads)
    half4 ha[8];
#pragma unroll
    for (int kt = 0; kt < 8; ++kt)
        ha[kt] = *(const half4*)(sm + HSO + ldsoff(PSH, w * 16 + ml, kt * 16 + gq * 4));
#pragma unroll
    for (int nt = 0; nt < 4; ++nt) {
        const int o = nt * 16 + ml;
        const bool valid = o < 60;
        float bv = valid ? B2[a * 60 + o] : 0.f;
        f32x4 acc = {bv, bv, bv, bv};
#pragma unroll
        for (int kt = 0; kt < 8; ++kt) {
            half4 b;
            if (valid) {
                const float* p2 = W2 + (size_t)a * 7680 + (kt * 16 + gq * 4) * 60 + o;
                b = half4{(_Float16)p2[0], (_Float16)p2[60],
                          (_Float16)p2[120], (_Float16)p2[180]};
            } else {
                b = half4{0, 0, 0, 0};
            }
            acc = MFMA16(ha[kt], b, acc);
        }
        if (valid) {
            float* op = out + (size_t)a * 192000 + (size_t)(rowbase + gq * 4) * 60 + o;
            op[0]   = acc.x;
            op[60]  = acc.y;
            op[120] = acc.z;
            op[180] = acc.w;
        }
    }
}

// =====================================================================
extern "C" void kernel_launch(void* const* d_in, const int* in_sizes, int n_in,
                              void* d_out, int out_size, void* d_ws, size_t ws_size,
                              hipStream_t stream)
{
    const float* agent_feature = (const float*)d_in[2];
    const float* map_feature   = (const float*)d_in[3];
    const float* obj_feature   = (const float*)d_in[6];
    const float* aW0 = (const float*)d_in[7];  const float* aB0 = (const float*)d_in[8];
    const float* aW1 = (const float*)d_in[9];  const float* aB1 = (const float*)d_in[10];
    const float* aW2 = (const float*)d_in[11]; const float* aB2 = (const float*)d_in[12];
    const float* mW0 = (const float*)d_in[13]; const float* mB0 = (const float*)d_in[14];
    const float* mW1 = (const float*)d_in[15]; const float* mB1 = (const float*)d_in[16];
    const float* mW2 = (const float*)d_in[17]; const float* mB2 = (const float*)d_in[18];
    const float* oW0 = (const float*)d_in[19]; const float* oB0 = (const float*)d_in[20];
    const float* oW1 = (const float*)d_in[21]; const float* oB1 = (const float*)d_in[22];
    const float* oW2 = (const float*)d_in[23]; const float* oB2 = (const float*)d_in[24];
    const float* Wq = (const float*)d_in[25];
    const float* Wk = (const float*)d_in[26];
    const float* Wv = (const float*)d_in[27];
    const float* mlpW1 = (const float*)d_in[28]; const float* mlpB1 = (const float*)d_in[29];
    const float* mlpW2 = (const float*)d_in[30]; const float* mlpB2 = (const float*)d_in[31];

    float* xbuf = (float*)d_ws;                    // [T,100,128] f32
    float* obuf = xbuf + 409600;                   // [T,100,128] f32
    _Float16* qh = (_Float16*)(obuf + 409600);     // [T,112,128] f16
    _Float16* kh = qh + 458752;
    _Float16* vh = kh + 458752;
    float* outp = (float*)d_out;

    // polyline subgraphs -> x [T, E=100, 128]
    subnet_mfma<4, 1><<<dim3(4 * 32), 256, 0, stream>>>(
        agent_feature, aW0, aB0, aW1, aB1, aW2, aB2, xbuf, 0);
    subnet_mfma<4, 0><<<dim3(64 * 32), 256, 0, stream>>>(
        map_feature, mW0, mB0, mW1, mB1, mW2, mB2, xbuf, 4);
    subnet_mfma<2, 0><<<dim3(32 * 32), 256, 0, stream>>>(
        obj_feature, oW0, oB0, oW1, oB1, oW2, oB2, xbuf, 68);

    qkv_kernel<<<dim3(TT), 256, 0, stream>>>(xbuf, Wq, Wk, Wv, qh, kh, vh);
    attn_kernel<<<dim3(TT), 256, 0, stream>>>(qh, kh, vh, obuf);
    mlp_kernel<<<dim3(50, 4), 256, 0, stream>>>(obuf, mlpW1, mlpB1, mlpW2, mlpB2, outp);
}

// Round 4
// 122.222 us; speedup vs baseline: 10.1087x; 1.6686x over previous
//
#include <hip/hip_runtime.h>
#include <hip/hip_fp16.h>

#define TT 32
#define EN 100
#define DD 128

typedef _Float16 half4 __attribute__((ext_vector_type(4)));
typedef float f32x4 __attribute__((ext_vector_type(4)));

#define MFMA16(a, b, c) __builtin_amdgcn_mfma_f32_16x16x16f16((a), (b), (c), 0, 0, 0)

__device__ __forceinline__ float nan0f(float v) { return (v == v) ? v : 0.f; }

__device__ __forceinline__ float ftanh(float x) {
    x = fminf(9.f, fmaxf(-9.f, x));
    float e = __expf(2.f * x);
    return (e - 1.f) / (e + 1.f);
}

// 2-panel (64-col) f16 tile, row stride 136B, XOR swizzle on byte bits 4-5.
__device__ __forceinline__ int ldsoff(int ps, int row, int col) {
    int b = (col >> 6) * ps + row * 136 + ((col & 63) << 1);
    return b ^ ((row & 12) << 2);
}

// ---------------- packed-weight geometry (offsets in half4 units) ----------
// B-fragment order: idx = (((kt*ntc + nt)*4 + gq)*16 + ml), value = half4 over
// rows kt*16+gq*4+j (j=0..3), col nt*16+ml.
#define OFF_AW   0          // subnet a: W0(256) W1b(1024) W2b(1024)
#define OFF_MW   2304
#define OFF_OW   4608
#define OFF_QKV  6912       // 3 x 4096
#define OFF_MW1  19200      // 4 x 4096
#define OFF_MW2  35584      // 4 x 2048
#define WPK_H4   43776

struct PackArgs {
    const float* src[20];
    int C[20], VC[20], ktc[20], ntc[20], dsto[20];
};

__global__ __launch_bounds__(256) void pack_w(PackArgs pa, _Float16* __restrict__ dst)
{
    const int s = blockIdx.y;
    const int total = pa.ktc[s] * pa.ntc[s] * 64;
    const int i = blockIdx.x * 256 + threadIdx.x;
    if (i >= total) return;
    const int ml = i & 15, gq = (i >> 4) & 3, rest = i >> 6;
    const int ntc = pa.ntc[s];
    const int nt = rest % ntc, kt = rest / ntc;
    const int col = nt * 16 + ml, row0 = kt * 16 + gq * 4;
    const float* W = pa.src[s];
    const int C = pa.C[s], VC = pa.VC[s];
    half4 v;
#pragma unroll
    for (int j = 0; j < 4; ++j)
        v[j] = (col < VC) ? (_Float16)W[(size_t)(row0 + j) * C + col] : (_Float16)0.f;
    *(half4*)(dst + ((size_t)pa.dsto[s] + i) * 4) = v;
}

// =====================================================================
// MFMA subnet: 1 block = 1 (g,t) polyline. Packed f16 B-frags (half4
// loads, no converts); cvec parallelized across 4 waves; (256,2) so
// nothing spills.
// =====================================================================
template<int MT, int DO_NAN0>
__global__ __launch_bounds__(256, 2) void subnet_mfma(
    const float* __restrict__ feat,
    const _Float16* __restrict__ wp,     // packed: W0 @0, W1b @256*4, W2b @1280*4
    const float* __restrict__ B0,
    const float* __restrict__ W1, const float* __restrict__ B1,
    const float* __restrict__ W2, const float* __restrict__ B2,
    float* __restrict__ xout, int e_off)
{
    constexpr int N = MT * 64;
    const int g = blockIdx.x >> 5;
    const int t = blockIdx.x & 31;
    const int tid = threadIdx.x;
    const int w = tid >> 6;
    const int lane = tid & 63;
    const int ml = lane & 15;
    const int gq = lane >> 4;
    const int rowbase = w * (16 * MT);

    __shared__ __attribute__((aligned(16))) unsigned char Hs[N * 144];
    __shared__ float red[4][64];
    __shared__ float part[4][64];
    __shared__ float cvec[64];

    const int Xw = gq << 4;
    const int Xr = (ml >> 2) << 4;

    f32x4 acc[MT][4];

    auto epilogue = [&](bool store) {
#pragma unroll
        for (int nt = 0; nt < 4; ++nt) {
            float am = 0.f;
#pragma unroll
            for (int mt = 0; mt < MT; ++mt) {
                f32x4 v = acc[mt][nt];
                v.x = fmaxf(v.x, 0.f); v.y = fmaxf(v.y, 0.f);
                v.z = fmaxf(v.z, 0.f); v.w = fmaxf(v.w, 0.f);
                am = fmaxf(am, fmaxf(fmaxf(v.x, v.y), fmaxf(v.z, v.w)));
                if (store) {
                    const int a0 = (rowbase + mt * 16 + gq * 4) * 144 + (nt * 16 + ml) * 2;
                    *(_Float16*)(Hs + ((a0      ) ^ Xw)) = (_Float16)v.x;
                    *(_Float16*)(Hs + ((a0 + 144) ^ Xw)) = (_Float16)v.y;
                    *(_Float16*)(Hs + ((a0 + 288) ^ Xw)) = (_Float16)v.z;
                    *(_Float16*)(Hs + ((a0 + 432) ^ Xw)) = (_Float16)v.w;
                }
            }
            am = fmaxf(am, __shfl_xor(am, 16, 64));
            am = fmaxf(am, __shfl_xor(am, 32, 64));
            if (lane < 16) red[w][nt * 16 + lane] = am;
        }
        __syncthreads();
    };

    // cvec[n] = Bn[n] + sum_k agg[k]*Wn[(64+k)*64+n], k-split across waves
    auto make_cvec = [&](const float* __restrict__ Wn, const float* __restrict__ Bn) {
        float a = fmaxf(fmaxf(red[0][lane], red[1][lane]),
                        fmaxf(red[2][lane], red[3][lane]));
        float s = 0.f;
#pragma unroll
        for (int kk = 0; kk < 16; ++kk) {
            int k = w * 16 + kk;
            s = fmaf(__shfl(a, k, 64), Wn[(size_t)(64 + k) * 64 + lane], s);
        }
        part[w][lane] = s;
        __syncthreads();
        if (w == 0)
            cvec[lane] = Bn[lane] + part[0][lane] + part[1][lane]
                       + part[2][lane] + part[3][lane];
        __syncthreads();
    };

    // ---------------- layer 0 ----------------
    {
#pragma unroll
        for (int nt = 0; nt < 4; ++nt) {
            float b = B0[nt * 16 + ml];
#pragma unroll
            for (int mt = 0; mt < MT; ++mt) acc[mt][nt] = f32x4{b, b, b, b};
        }
        half4 bf[4];
#pragma unroll
        for (int nt = 0; nt < 4; ++nt)
            bf[nt] = *(const half4*)(wp + (size_t)(((nt * 4 + gq) * 16 + ml) * 4));
        const float* xb = feat + (size_t)(g * TT + t) * N * 16;
#pragma unroll
        for (int mt = 0; mt < MT; ++mt) {
            float4 xv = *reinterpret_cast<const float4*>(
                xb + (size_t)(rowbase + mt * 16 + ml) * 16 + gq * 4);
            if (DO_NAN0) {
                xv.x = nan0f(xv.x); xv.y = nan0f(xv.y);
                xv.z = nan0f(xv.z); xv.w = nan0f(xv.w);
            }
            half4 af = half4{(_Float16)xv.x, (_Float16)xv.y,
                             (_Float16)xv.z, (_Float16)xv.w};
#pragma unroll
            for (int nt = 0; nt < 4; ++nt)
                acc[mt][nt] = MFMA16(af, bf[nt], acc[mt][nt]);
        }
    }
    epilogue(true);
    make_cvec(W1, B1);

    auto layer = [&](const _Float16* __restrict__ wb, bool store) {
#pragma unroll
        for (int nt = 0; nt < 4; ++nt) {
            float cv = cvec[nt * 16 + ml];
#pragma unroll
            for (int mt = 0; mt < MT; ++mt) acc[mt][nt] = f32x4{cv, cv, cv, cv};
        }
#pragma unroll
        for (int kt = 0; kt < 4; ++kt) {
            half4 bf[4];
#pragma unroll
            for (int nt = 0; nt < 4; ++nt)
                bf[nt] = *(const half4*)(wb +
                    (size_t)(((((kt * 4 + nt) * 4) + gq) * 16 + ml) * 4));
#pragma unroll
            for (int mt = 0; mt < MT; ++mt) {
                const int addr = (((rowbase + mt * 16 + ml) * 144) + kt * 32 + gq * 8) ^ Xr;
                half4 af = *reinterpret_cast<const half4*>(Hs + addr);
#pragma unroll
                for (int nt = 0; nt < 4; ++nt)
                    acc[mt][nt] = MFMA16(af, bf[nt], acc[mt][nt]);
            }
        }
        epilogue(store);
    };

    layer(wp + 256 * 4, true);
    make_cvec(W2, B2);
    layer(wp + 1280 * 4, false);

    if (w == 0) {
        float a = fmaxf(fmaxf(red[0][lane], red[1][lane]),
                        fmaxf(red[2][lane], red[3][lane]));
        size_t base = ((size_t)t * EN + (e_off + g)) * DD;
        xout[base + lane] = a;
        xout[base + 64 + lane] = a;
    }
}

// =====================================================================
// QKV: grid (t, tgt). X staged f16 LDS; W-frags direct from packed global.
// =====================================================================
#define PSX 15232          // 112*136
#define WSO 30464          // X region size (2 panels)

__global__ __launch_bounds__(256) void qkv_kernel(
    const float* __restrict__ xbuf, const _Float16* __restrict__ wqkv,
    _Float16* __restrict__ qh, _Float16* __restrict__ kh, _Float16* __restrict__ vh)
{
    const int t = blockIdx.x;
    const int tgt = blockIdx.y;
    const int tid = threadIdx.x;
    const int w = tid >> 6, lane = tid & 63, ml = lane & 15, gq = lane >> 4;

    __shared__ __attribute__((aligned(16))) unsigned char sm[WSO];

    const _Float16* wb = wqkv + (size_t)tgt * 4096 * 4;
    _Float16* Oh = (tgt == 0) ? qh : (tgt == 1) ? kh : vh;

    for (int i = tid; i < 112 * 32; i += 256) {
        int row = i >> 5, c4 = (i & 31) << 2;
        half4 v;
        if (row < EN) {
            float4 f = *reinterpret_cast<const float4*>(
                xbuf + (size_t)t * EN * DD + row * DD + c4);
            v = half4{(_Float16)f.x, (_Float16)f.y, (_Float16)f.z, (_Float16)f.w};
        } else {
            v = half4{0, 0, 0, 0};
        }
        *(half4*)(sm + ldsoff(PSX, row, c4)) = v;
    }
    __syncthreads();

#pragma unroll 1
    for (int mi = 0; mi < 2; ++mi) {
        int mt = w + (mi << 2);
        if (mt >= 7) continue;
        half4 xa[8];
#pragma unroll
        for (int kt = 0; kt < 8; ++kt)
            xa[kt] = *(const half4*)(sm + ldsoff(PSX, mt * 16 + ml, kt * 16 + gq * 4));
#pragma unroll
        for (int nt = 0; nt < 8; ++nt) {
            f32x4 acc = {0.f, 0.f, 0.f, 0.f};
#pragma unroll
            for (int kt = 0; kt < 8; ++kt) {
                half4 b = *(const half4*)(wb +
                    (size_t)(((((kt * 8 + nt) * 4) + gq) * 16 + ml) * 4));
                acc = MFMA16(xa[kt], b, acc);
            }
            _Float16* op = Oh + (size_t)t * 14336 + (mt * 16 + gq * 4) * 128 + nt * 16 + ml;
            op[0]   = (_Float16)acc.x;
            op[128] = (_Float16)acc.y;
            op[256] = (_Float16)acc.z;
            op[384] = (_Float16)acc.w;
        }
    }
}

// =====================================================================
// Attention: grid (t, 2). Block rb handles mt = rb*4 + w (rb1: 3 waves).
// K,V staged f16 LDS; Q frags from global; P overwrites K region.
// =====================================================================
#define VSO 30464

__global__ __launch_bounds__(256) void attn_kernel(
    const _Float16* __restrict__ qh, const _Float16* __restrict__ kh,
    const _Float16* __restrict__ vh, float* __restrict__ obuf)
{
    const int t = blockIdx.x;
    const int rb = blockIdx.y;
    const int tid = threadIdx.x;
    const int w = tid >> 6, lane = tid & 63, ml = lane & 15, gq = lane >> 4;

    __shared__ __attribute__((aligned(16))) unsigned char sm[2 * WSO];

    for (int i = tid; i < 112 * 32; i += 256) {
        int row = i >> 5, c4 = (i & 31) << 2;
        size_t src = (size_t)t * 14336 + row * 128 + c4;
        *(half4*)(sm + ldsoff(PSX, row, c4))       = *(const half4*)(kh + src);
        *(half4*)(sm + VSO + ldsoff(PSX, row, c4)) = *(const half4*)(vh + src);
    }
    __syncthreads();

    const float scale = 0.088388347648318447f;   // 1/sqrt(128)
    const int mt = rb * 4 + w;
    const bool act = mt < 7;
    half4 pf[7];

    if (act) {
        half4 qa[8];
#pragma unroll
        for (int kt = 0; kt < 8; ++kt)
            qa[kt] = *(const half4*)(qh + (size_t)t * 14336 + (mt * 16 + ml) * 128
                                     + kt * 16 + gq * 4);
        f32x4 sacc[7];
#pragma unroll
        for (int nt = 0; nt < 7; ++nt) {
            f32x4 acc = {0.f, 0.f, 0.f, 0.f};
#pragma unroll
            for (int kt = 0; kt < 8; ++kt) {
                half4 b = *(const half4*)(sm + ldsoff(PSX, nt * 16 + ml, kt * 16 + gq * 4));
                acc = MFMA16(qa[kt], b, acc);
            }
            sacc[nt].x = acc.x * scale; sacc[nt].y = acc.y * scale;
            sacc[nt].z = acc.z * scale; sacc[nt].w = acc.w * scale;
        }
        float mx[4] = {-3e38f, -3e38f, -3e38f, -3e38f};
#pragma unroll
        for (int nt = 0; nt < 7; ++nt) {
            if (nt < 6 || ml < 4) {
                mx[0] = fmaxf(mx[0], sacc[nt].x); mx[1] = fmaxf(mx[1], sacc[nt].y);
                mx[2] = fmaxf(mx[2], sacc[nt].z); mx[3] = fmaxf(mx[3], sacc[nt].w);
            }
        }
#pragma unroll
        for (int m = 1; m <= 8; m <<= 1) {
#pragma unroll
            for (int i = 0; i < 4; ++i) mx[i] = fmaxf(mx[i], __shfl_xor(mx[i], m, 64));
        }
        float sum[4] = {0.f, 0.f, 0.f, 0.f};
#pragma unroll
        for (int nt = 0; nt < 7; ++nt) {
            bool v = (nt < 6) || (ml < 4);
            float p0 = v ? __expf(sacc[nt].x - mx[0]) : 0.f;
            float p1 = v ? __expf(sacc[nt].y - mx[1]) : 0.f;
            float p2 = v ? __expf(sacc[nt].z - mx[2]) : 0.f;
            float p3 = v ? __expf(sacc[nt].w - mx[3]) : 0.f;
            sum[0] += p0; sum[1] += p1; sum[2] += p2; sum[3] += p3;
            sacc[nt] = f32x4{p0, p1, p2, p3};
        }
#pragma unroll
        for (int m = 1; m <= 8; m <<= 1) {
#pragma unroll
            for (int i = 0; i < 4; ++i) sum[i] += __shfl_xor(sum[i], m, 64);
        }
        float inv[4] = {1.f / sum[0], 1.f / sum[1], 1.f / sum[2], 1.f / sum[3]};
#pragma unroll
        for (int nt = 0; nt < 7; ++nt)
            pf[nt] = half4{(_Float16)(sacc[nt].x * inv[0]), (_Float16)(sacc[nt].y * inv[1]),
                           (_Float16)(sacc[nt].z * inv[2]), (_Float16)(sacc[nt].w * inv[3])};
    }

    __syncthreads();   // all S reads of K done

    if (act) {
        const int row0 = mt * 16 + gq * 4;
#pragma unroll
        for (int nt = 0; nt < 7; ++nt) {
            const int col = nt * 16 + ml;
            *(_Float16*)(sm + ldsoff(PSX, row0 + 0, col)) = pf[nt].x;
            *(_Float16*)(sm + ldsoff(PSX, row0 + 1, col)) = pf[nt].y;
            *(_Float16*)(sm + ldsoff(PSX, row0 + 2, col)) = pf[nt].z;
            *(_Float16*)(sm + ldsoff(PSX, row0 + 3, col)) = pf[nt].w;
        }
    }
    __syncthreads();

    if (act) {
        half4 pa[7];
#pragma unroll
        for (int kt = 0; kt < 7; ++kt)
            pa[kt] = *(const half4*)(sm + ldsoff(PSX, mt * 16 + ml, kt * 16 + gq * 4));
#pragma unroll
        for (int nt = 0; nt < 8; ++nt) {
            f32x4 acc = {0.f, 0.f, 0.f, 0.f};
            const int col = nt * 16 + ml;
#pragma unroll
            for (int kt = 0; kt < 7; ++kt) {
                const int r0 = kt * 16 + gq * 4;
                half4 b = half4{
                    *(const _Float16*)(sm + VSO + ldsoff(PSX, r0 + 0, col)),
                    *(const _Float16*)(sm + VSO + ldsoff(PSX, r0 + 1, col)),
                    *(const _Float16*)(sm + VSO + ldsoff(PSX, r0 + 2, col)),
                    *(const _Float16*)(sm + VSO + ldsoff(PSX, r0 + 3, col))};
                acc = MFMA16(pa[kt], b, acc);
            }
            const int row0 = mt * 16 + gq * 4;
            float* op = obuf + (size_t)t * EN * DD + row0 * DD + col;
            if (row0 + 0 < EN) op[0]       = acc.x;
            if (row0 + 1 < EN) op[DD]      = acc.y;
            if (row0 + 2 < EN) op[2 * DD]  = acc.z;
            if (row0 + 3 < EN) op[3 * DD]  = acc.w;
        }
    }
}

// =====================================================================
// MLP head: block = (64 rows, agent a). Packed W1/W2 frags from global,
// hdn wave-private in LDS (no barriers), fast tanh.
// =====================================================================
#define PSH 8704           // 64*136

__global__ __launch_bounds__(256) void mlp_kernel(
    const float* __restrict__ obuf, const _Float16* __restrict__ wpk,
    const float* __restrict__ B1, const float* __restrict__ B2,
    float* __restrict__ out)
{
    const int a = blockIdx.y;
    const int tid = threadIdx.x;
    const int w = tid >> 6, lane = tid & 63, ml = lane & 15, gq = lane >> 4;
    const int rowbase = blockIdx.x * 64 + w * 16;

    __shared__ __attribute__((aligned(16))) unsigned char sm[PSH * 2];

    const _Float16* w1b = wpk + ((size_t)OFF_MW1 + a * 4096) * 4;
    const _Float16* w2b = wpk + ((size_t)OFF_MW2 + a * 2048) * 4;

    // layer 1: hdn = tanh(O @ W1 + b1) -> LDS f16 (wave-private rows)
    half4 xa[8];
#pragma unroll
    for (int kt = 0; kt < 8; ++kt) {
        float4 f = *reinterpret_cast<const float4*>(
            obuf + (size_t)(rowbase + ml) * 128 + kt * 16 + gq * 4);
        xa[kt] = half4{(_Float16)f.x, (_Float16)f.y, (_Float16)f.z, (_Float16)f.w};
    }
#pragma unroll
    for (int nt = 0; nt < 8; ++nt) {
        const int col = nt * 16 + ml;
        float bv = B1[a * 128 + col];
        f32x4 acc = {bv, bv, bv, bv};
#pragma unroll
        for (int kt = 0; kt < 8; ++kt) {
            half4 b = *(const half4*)(w1b +
                (size_t)(((((kt * 8 + nt) * 4) + gq) * 16 + ml) * 4));
            acc = MFMA16(xa[kt], b, acc);
        }
        const int lr0 = w * 16 + gq * 4;
        *(_Float16*)(sm + ldsoff(PSH, lr0 + 0, col)) = (_Float16)ftanh(acc.x);
        *(_Float16*)(sm + ldsoff(PSH, lr0 + 1, col)) = (_Float16)ftanh(acc.y);
        *(_Float16*)(sm + ldsoff(PSH, lr0 + 2, col)) = (_Float16)ftanh(acc.z);
        *(_Float16*)(sm + ldsoff(PSH, lr0 + 3, col)) = (_Float16)ftanh(acc.w);
    }

    // layer 2: out = hdn @ W2 + b2 (cols 60; packed W2 zero-padded to 64)
    half4 ha[8];
#pragma unroll
    for (int kt = 0; kt < 8; ++kt)
        ha[kt] = *(const half4*)(sm + ldsoff(PSH, w * 16 + ml, kt * 16 + gq * 4));
#pragma unroll
    for (int nt = 0; nt < 4; ++nt) {
        const int o = nt * 16 + ml;
        const bool valid = o < 60;
        float bv = valid ? B2[a * 60 + o] : 0.f;
        f32x4 acc = {bv, bv, bv, bv};
#pragma unroll
        for (int kt = 0; kt < 8; ++kt) {
            half4 b = *(const half4*)(w2b +
                (size_t)(((((kt * 4 + nt) * 4) + gq) * 16 + ml) * 4));
            acc = MFMA16(ha[kt], b, acc);
        }
        if (valid) {
            float* op = out + (size_t)a * 192000 + (size_t)(rowbase + gq * 4) * 60 + o;
            op[0]   = acc.x;
            op[60]  = acc.y;
            op[120] = acc.z;
            op[180] = acc.w;
        }
    }
}

// =====================================================================
extern "C" void kernel_launch(void* const* d_in, const int* in_sizes, int n_in,
                              void* d_out, int out_size, void* d_ws, size_t ws_size,
                              hipStream_t stream)
{
    const float* agent_feature = (const float*)d_in[2];
    const float* map_feature   = (const float*)d_in[3];
    const float* obj_feature   = (const float*)d_in[6];
    const float* aW0 = (const float*)d_in[7];  const float* aB0 = (const float*)d_in[8];
    const float* aW1 = (const float*)d_in[9];  const float* aB1 = (const float*)d_in[10];
    const float* aW2 = (const float*)d_in[11]; const float* aB2 = (const float*)d_in[12];
    const float* mW0 = (const float*)d_in[13]; const float* mB0 = (const float*)d_in[14];
    const float* mW1 = (const float*)d_in[15]; const float* mB1 = (const float*)d_in[16];
    const float* mW2 = (const float*)d_in[17]; const float* mB2 = (const float*)d_in[18];
    const float* oW0 = (const float*)d_in[19]; const float* oB0 = (const float*)d_in[20];
    const float* oW1 = (const float*)d_in[21]; const float* oB1 = (const float*)d_in[22];
    const float* oW2 = (const float*)d_in[23]; const float* oB2 = (const float*)d_in[24];
    const float* Wq = (const float*)d_in[25];
    const float* Wk = (const float*)d_in[26];
    const float* Wv = (const float*)d_in[27];
    const float* mlpW1 = (const float*)d_in[28]; const float* mlpB1 = (const float*)d_in[29];
    const float* mlpW2 = (const float*)d_in[30]; const float* mlpB2 = (const float*)d_in[31];

    float* xbuf = (float*)d_ws;                    // [T,100,128] f32
    float* obuf = xbuf + 409600;                   // [T,100,128] f32
    _Float16* qh = (_Float16*)(obuf + 409600);     // [T,112,128] f16
    _Float16* kh = qh + 458752;
    _Float16* vh = kh + 458752;
    _Float16* wpk = vh + 458752;                   // packed weights, 175104 halfs

    float* outp = (float*)d_out;

    // ---- pack all weights to f16 fragments (one launch) ----
    PackArgs pa;
    auto seg = [&](int s, const float* src, int C, int VC, int ktc, int ntc, int dsto) {
        pa.src[s] = src; pa.C[s] = C; pa.VC[s] = VC;
        pa.ktc[s] = ktc; pa.ntc[s] = ntc; pa.dsto[s] = dsto;
    };
    seg(0, aW0, 64, 64, 1, 4, OFF_AW);
    seg(1, aW1, 64, 64, 4, 4, OFF_AW + 256);
    seg(2, aW2, 64, 64, 4, 4, OFF_AW + 1280);
    seg(3, mW0, 64, 64, 1, 4, OFF_MW);
    seg(4, mW1, 64, 64, 4, 4, OFF_MW + 256);
    seg(5, mW2, 64, 64, 4, 4, OFF_MW + 1280);
    seg(6, oW0, 64, 64, 1, 4, OFF_OW);
    seg(7, oW1, 64, 64, 4, 4, OFF_OW + 256);
    seg(8, oW2, 64, 64, 4, 4, OFF_OW + 1280);
    seg(9,  Wq, 128, 128, 8, 8, OFF_QKV);
    seg(10, Wk, 128, 128, 8, 8, OFF_QKV + 4096);
    seg(11, Wv, 128, 128, 8, 8, OFF_QKV + 8192);
    for (int a = 0; a < 4; ++a) {
        seg(12 + a, mlpW1 + (size_t)a * 16384, 128, 128, 8, 8, OFF_MW1 + a * 4096);
        seg(16 + a, mlpW2 + (size_t)a * 7680,  60,  60,  8, 4, OFF_MW2 + a * 2048);
    }
    pack_w<<<dim3(16, 20), 256, 0, stream>>>(pa, wpk);

    // polyline subgraphs -> x [T, E=100, 128]
    subnet_mfma<4, 1><<<dim3(4 * 32), 256, 0, stream>>>(
        agent_feature, wpk + OFF_AW * 4, aB0, aW1, aB1, aW2, aB2, xbuf, 0);
    subnet_mfma<4, 0><<<dim3(64 * 32), 256, 0, stream>>>(
        map_feature, wpk + OFF_MW * 4, mB0, mW1, mB1, mW2, mB2, xbuf, 4);
    subnet_mfma<2, 0><<<dim3(32 * 32), 256, 0, stream>>>(
        obj_feature, wpk + OFF_OW * 4, oB0, oW1, oB1, oW2, oB2, xbuf, 68);

    qkv_kernel<<<dim3(TT, 3), 256, 0, stream>>>(xbuf, wpk + OFF_QKV * 4, qh, kh, vh);
    attn_kernel<<<dim3(TT, 2), 256, 0, stream>>>(qh, kh, vh, obuf);
    mlp_kernel<<<dim3(50, 4), 256, 0, stream>>>(obuf, wpk, mlpB1, mlpB2, outp);
}

// Round 5
// 118.535 us; speedup vs baseline: 10.4232x; 1.0311x over previous
//
#include <hip/hip_runtime.h>
#include <hip/hip_fp16.h>

#define TT 32
#define EN 100
#define DD 128

typedef _Float16 half4 __attribute__((ext_vector_type(4)));
typedef float f32x4 __attribute__((ext_vector_type(4)));

#define MFMA16(a, b, c) __builtin_amdgcn_mfma_f32_16x16x16f16((a), (b), (c), 0, 0, 0)

__device__ __forceinline__ float nan0f(float v) { return (v == v) ? v : 0.f; }

__device__ __forceinline__ float ftanh(float x) {
    x = fminf(9.f, fmaxf(-9.f, x));
    float e = __expf(2.f * x);
    return (e - 1.f) / (e + 1.f);
}

// 2-panel (64-col) f16 tile, row stride 136B, XOR swizzle on byte bits 4-5.
__device__ __forceinline__ int ldsoff(int ps, int row, int col) {
    int b = (col >> 6) * ps + row * 136 + ((col & 63) << 1);
    return b ^ ((row & 12) << 2);
}

// single-panel (64-col) variant for the subnet H tile
__device__ __forceinline__ int hoff(int row, int col) {
    return (row * 136 + (col << 1)) ^ ((row & 12) << 2);
}

// ---------------- packed-weight geometry (offsets in half4 units) ----------
#define OFF_AW   0          // subnet a: W0(256) W1b(1024) W2b(1024)
#define OFF_MW   2304
#define OFF_OW   4608
#define OFF_QKV  6912       // 3 x 4096
#define OFF_MW1  19200      // 4 x 4096
#define OFF_MW2  35584      // 4 x 2048
#define WPK_H4   43776

struct PackArgs {
    const float* src[20];
    int C[20], VC[20], ktc[20], ntc[20], dsto[20];
};

__global__ __launch_bounds__(256) void pack_w(PackArgs pa, _Float16* __restrict__ dst)
{
    const int s = blockIdx.y;
    const int total = pa.ktc[s] * pa.ntc[s] * 64;
    const int i = blockIdx.x * 256 + threadIdx.x;
    if (i >= total) return;
    const int ml = i & 15, gq = (i >> 4) & 3, rest = i >> 6;
    const int ntc = pa.ntc[s];
    const int nt = rest % ntc, kt = rest / ntc;
    const int col = nt * 16 + ml, row0 = kt * 16 + gq * 4;
    const float* W = pa.src[s];
    const int C = pa.C[s], VC = pa.VC[s];
    half4 v;
#pragma unroll
    for (int j = 0; j < 4; ++j)
        v[j] = (col < VC) ? (_Float16)W[(size_t)(row0 + j) * C + col] : (_Float16)0.f;
    *(half4*)(dst + ((size_t)pa.dsto[s] + i) * 4) = v;
}

// =====================================================================
// Merged subnet: grid 3200, 512-thr blocks (8 waves), MT<=2 per wave.
// Segment (agent/map/obj) selected by block-id range. H wave-private in
// LDS f16 (stride 136 + XOR swizzle); 8-wide reductions.
// =====================================================================
struct SubArgs {
    const float* feat[3];
    const _Float16* wp[3];
    const float* B0[3];
    const float* W1[3]; const float* B1[3];
    const float* W2[3]; const float* B2[3];
    int e_base[3];
    int lo[3];     // 0, 128, 2176
    int mtl[3];    // 2, 2, 1
    int dn[3];     // 1, 0, 0
};

__global__ __launch_bounds__(512, 6) void subnet_uber(SubArgs sa, float* __restrict__ xout)
{
    const int bid = blockIdx.x;
    const int s = (bid >= sa.lo[1]) + (bid >= sa.lo[2]);
    const int idx = bid - sa.lo[s];
    const int g = idx >> 5, t = idx & 31;
    const int mtl = sa.mtl[s];
    const int N = mtl << 7;                    // 256 or 128
    const int tid = threadIdx.x;
    const int w = tid >> 6, lane = tid & 63, ml = lane & 15, gq = lane >> 4;
    const int rowbase = w * 16 * mtl;

    __shared__ __attribute__((aligned(16))) unsigned char Hs[256 * 136];
    __shared__ float red[8][64];
    __shared__ float part[8][64];
    __shared__ float cvec[64];

    f32x4 acc[2][4];

    auto epilogue = [&](bool store) {
#pragma unroll
        for (int nt = 0; nt < 4; ++nt) {
            float am = 0.f;
#pragma unroll
            for (int mt = 0; mt < 2; ++mt) {
                if (mt < mtl) {
                    f32x4 v = acc[mt][nt];
                    v.x = fmaxf(v.x, 0.f); v.y = fmaxf(v.y, 0.f);
                    v.z = fmaxf(v.z, 0.f); v.w = fmaxf(v.w, 0.f);
                    am = fmaxf(am, fmaxf(fmaxf(v.x, v.y), fmaxf(v.z, v.w)));
                    if (store) {
                        const int r0 = rowbase + mt * 16 + gq * 4;
                        const int c = nt * 16 + ml;
                        *(_Float16*)(Hs + hoff(r0 + 0, c)) = (_Float16)v.x;
                        *(_Float16*)(Hs + hoff(r0 + 1, c)) = (_Float16)v.y;
                        *(_Float16*)(Hs + hoff(r0 + 2, c)) = (_Float16)v.z;
                        *(_Float16*)(Hs + hoff(r0 + 3, c)) = (_Float16)v.w;
                    }
                }
            }
            am = fmaxf(am, __shfl_xor(am, 16, 64));
            am = fmaxf(am, __shfl_xor(am, 32, 64));
            if (lane < 16) red[w][nt * 16 + lane] = am;
        }
        __syncthreads();
    };

    // cvec[n] = Bn[n] + sum_k agg[k]*Wn[(64+k)*64+n]; k split 8 ways
    auto make_cvec = [&](const float* Wn, const float* Bn) {
        float a = red[0][lane];
#pragma unroll
        for (int ww = 1; ww < 8; ++ww) a = fmaxf(a, red[ww][lane]);
        float sum = 0.f;
#pragma unroll
        for (int kk = 0; kk < 8; ++kk) {
            int k = w * 8 + kk;
            sum = fmaf(__shfl(a, k, 64), Wn[(size_t)(64 + k) * 64 + lane], sum);
        }
        part[w][lane] = sum;
        __syncthreads();
        if (w == 0) {
            float c = Bn[lane];
#pragma unroll
            for (int ww = 0; ww < 8; ++ww) c += part[ww][lane];
            cvec[lane] = c;
        }
        __syncthreads();
    };

    const _Float16* wp = sa.wp[s];

    // ---------------- layer 0 ----------------
    {
        const float* B0 = sa.B0[s];
#pragma unroll
        for (int nt = 0; nt < 4; ++nt) {
            float b = B0[nt * 16 + ml];
            acc[0][nt] = f32x4{b, b, b, b};
            acc[1][nt] = f32x4{b, b, b, b};
        }
        half4 bf[4];
#pragma unroll
        for (int nt = 0; nt < 4; ++nt)
            bf[nt] = *(const half4*)(wp + (size_t)(((nt * 4 + gq) * 16 + ml) * 4));
        const float* xb = sa.feat[s] + (size_t)(g * TT + t) * N * 16;
        const int dn = sa.dn[s];
#pragma unroll
        for (int mt = 0; mt < 2; ++mt) {
            if (mt < mtl) {
                float4 xv = *reinterpret_cast<const float4*>(
                    xb + (size_t)(rowbase + mt * 16 + ml) * 16 + gq * 4);
                if (dn) {
                    xv.x = nan0f(xv.x); xv.y = nan0f(xv.y);
                    xv.z = nan0f(xv.z); xv.w = nan0f(xv.w);
                }
                half4 af = half4{(_Float16)xv.x, (_Float16)xv.y,
                                 (_Float16)xv.z, (_Float16)xv.w};
#pragma unroll
                for (int nt = 0; nt < 4; ++nt)
                    acc[mt][nt] = MFMA16(af, bf[nt], acc[mt][nt]);
            }
        }
    }
    epilogue(true);
    make_cvec(sa.W1[s], sa.B1[s]);

    auto layer = [&](const _Float16* wb, bool store) {
#pragma unroll
        for (int nt = 0; nt < 4; ++nt) {
            float cv = cvec[nt * 16 + ml];
            acc[0][nt] = f32x4{cv, cv, cv, cv};
            acc[1][nt] = f32x4{cv, cv, cv, cv};
        }
#pragma unroll
        for (int kt = 0; kt < 4; ++kt) {
            half4 bf[4];
#pragma unroll
            for (int nt = 0; nt < 4; ++nt)
                bf[nt] = *(const half4*)(wb +
                    (size_t)(((((kt * 4 + nt) * 4) + gq) * 16 + ml) * 4));
#pragma unroll
            for (int mt = 0; mt < 2; ++mt) {
                if (mt < mtl) {
                    half4 af = *(const half4*)(Hs +
                        hoff(rowbase + mt * 16 + ml, kt * 16 + gq * 4));
#pragma unroll
                    for (int nt = 0; nt < 4; ++nt)
                        acc[mt][nt] = MFMA16(af, bf[nt], acc[mt][nt]);
                }
            }
        }
        epilogue(store);
    };

    layer(wp + 256 * 4, true);
    make_cvec(sa.W2[s], sa.B2[s]);
    layer(wp + 1280 * 4, false);

    if (w == 0) {
        float a = red[0][lane];
#pragma unroll
        for (int ww = 1; ww < 8; ++ww) a = fmaxf(a, red[ww][lane]);
        size_t base = ((size_t)t * EN + (sa.e_base[s] + g)) * DD;
        xout[base + lane] = a;
        xout[base + 64 + lane] = a;
    }
}

// =====================================================================
// QKV: grid (t, tgt). X staged f16 LDS; W-frags direct from packed global.
// =====================================================================
#define PSX 15232          // 112*136
#define WSO 30464          // X region size (2 panels)

__global__ __launch_bounds__(256) void qkv_kernel(
    const float* __restrict__ xbuf, const _Float16* __restrict__ wqkv,
    _Float16* __restrict__ qh, _Float16* __restrict__ kh, _Float16* __restrict__ vh)
{
    const int t = blockIdx.x;
    const int tgt = blockIdx.y;
    const int tid = threadIdx.x;
    const int w = tid >> 6, lane = tid & 63, ml = lane & 15, gq = lane >> 4;

    __shared__ __attribute__((aligned(16))) unsigned char sm[WSO];

    const _Float16* wb = wqkv + (size_t)tgt * 4096 * 4;
    _Float16* Oh = (tgt == 0) ? qh : (tgt == 1) ? kh : vh;

    for (int i = tid; i < 112 * 32; i += 256) {
        int row = i >> 5, c4 = (i & 31) << 2;
        half4 v;
        if (row < EN) {
            float4 f = *reinterpret_cast<const float4*>(
                xbuf + (size_t)t * EN * DD + row * DD + c4);
            v = half4{(_Float16)f.x, (_Float16)f.y, (_Float16)f.z, (_Float16)f.w};
        } else {
            v = half4{0, 0, 0, 0};
        }
        *(half4*)(sm + ldsoff(PSX, row, c4)) = v;
    }
    __syncthreads();

#pragma unroll 1
    for (int mi = 0; mi < 2; ++mi) {
        int mt = w + (mi << 2);
        if (mt >= 7) continue;
        half4 xa[8];
#pragma unroll
        for (int kt = 0; kt < 8; ++kt)
            xa[kt] = *(const half4*)(sm + ldsoff(PSX, mt * 16 + ml, kt * 16 + gq * 4));
#pragma unroll
        for (int nt = 0; nt < 8; ++nt) {
            f32x4 acc = {0.f, 0.f, 0.f, 0.f};
#pragma unroll
            for (int kt = 0; kt < 8; ++kt) {
                half4 b = *(const half4*)(wb +
                    (size_t)(((((kt * 8 + nt) * 4) + gq) * 16 + ml) * 4));
                acc = MFMA16(xa[kt], b, acc);
            }
            _Float16* op = Oh + (size_t)t * 14336 + (mt * 16 + gq * 4) * 128 + nt * 16 + ml;
            op[0]   = (_Float16)acc.x;
            op[128] = (_Float16)acc.y;
            op[256] = (_Float16)acc.z;
            op[384] = (_Float16)acc.w;
        }
    }
}

// =====================================================================
// Attention: grid (t, 2). K,V staged f16 LDS; Q frags from global;
// in-register softmax; P overwrites K region.
// =====================================================================
#define VSO 30464

__global__ __launch_bounds__(256) void attn_kernel(
    const _Float16* __restrict__ qh, const _Float16* __restrict__ kh,
    const _Float16* __restrict__ vh, float* __restrict__ obuf)
{
    const int t = blockIdx.x;
    const int rb = blockIdx.y;
    const int tid = threadIdx.x;
    const int w = tid >> 6, lane = tid & 63, ml = lane & 15, gq = lane >> 4;

    __shared__ __attribute__((aligned(16))) unsigned char sm[2 * WSO];

    for (int i = tid; i < 112 * 32; i += 256) {
        int row = i >> 5, c4 = (i & 31) << 2;
        size_t src = (size_t)t * 14336 + row * 128 + c4;
        *(half4*)(sm + ldsoff(PSX, row, c4))       = *(const half4*)(kh + src);
        *(half4*)(sm + VSO + ldsoff(PSX, row, c4)) = *(const half4*)(vh + src);
    }
    __syncthreads();

    const float scale = 0.088388347648318447f;   // 1/sqrt(128)
    const int mt = rb * 4 + w;
    const bool act = mt < 7;
    half4 pf[7];

    if (act) {
        half4 qa[8];
#pragma unroll
        for (int kt = 0; kt < 8; ++kt)
            qa[kt] = *(const half4*)(qh + (size_t)t * 14336 + (mt * 16 + ml) * 128
                                     + kt * 16 + gq * 4);
        f32x4 sacc[7];
#pragma unroll
        for (int nt = 0; nt < 7; ++nt) {
            f32x4 acc = {0.f, 0.f, 0.f, 0.f};
#pragma unroll
            for (int kt = 0; kt < 8; ++kt) {
                half4 b = *(const half4*)(sm + ldsoff(PSX, nt * 16 + ml, kt * 16 + gq * 4));
                acc = MFMA16(qa[kt], b, acc);
            }
            sacc[nt].x = acc.x * scale; sacc[nt].y = acc.y * scale;
            sacc[nt].z = acc.z * scale; sacc[nt].w = acc.w * scale;
        }
        float mx[4] = {-3e38f, -3e38f, -3e38f, -3e38f};
#pragma unroll
        for (int nt = 0; nt < 7; ++nt) {
            if (nt < 6 || ml < 4) {
                mx[0] = fmaxf(mx[0], sacc[nt].x); mx[1] = fmaxf(mx[1], sacc[nt].y);
                mx[2] = fmaxf(mx[2], sacc[nt].z); mx[3] = fmaxf(mx[3], sacc[nt].w);
            }
        }
#pragma unroll
        for (int m = 1; m <= 8; m <<= 1) {
#pragma unroll
            for (int i = 0; i < 4; ++i) mx[i] = fmaxf(mx[i], __shfl_xor(mx[i], m, 64));
        }
        float sum[4] = {0.f, 0.f, 0.f, 0.f};
#pragma unroll
        for (int nt = 0; nt < 7; ++nt) {
            bool v = (nt < 6) || (ml < 4);
            float p0 = v ? __expf(sacc[nt].x - mx[0]) : 0.f;
            float p1 = v ? __expf(sacc[nt].y - mx[1]) : 0.f;
            float p2 = v ? __expf(sacc[nt].z - mx[2]) : 0.f;
            float p3 = v ? __expf(sacc[nt].w - mx[3]) : 0.f;
            sum[0] += p0; sum[1] += p1; sum[2] += p2; sum[3] += p3;
            sacc[nt] = f32x4{p0, p1, p2, p3};
        }
#pragma unroll
        for (int m = 1; m <= 8; m <<= 1) {
#pragma unroll
            for (int i = 0; i < 4; ++i) sum[i] += __shfl_xor(sum[i], m, 64);
        }
        float inv[4] = {1.f / sum[0], 1.f / sum[1], 1.f / sum[2], 1.f / sum[3]};
#pragma unroll
        for (int nt = 0; nt < 7; ++nt)
            pf[nt] = half4{(_Float16)(sacc[nt].x * inv[0]), (_Float16)(sacc[nt].y * inv[1]),
                           (_Float16)(sacc[nt].z * inv[2]), (_Float16)(sacc[nt].w * inv[3])};
    }

    __syncthreads();   // all S reads of K done

    if (act) {
        const int row0 = mt * 16 + gq * 4;
#pragma unroll
        for (int nt = 0; nt < 7; ++nt) {
            const int col = nt * 16 + ml;
            *(_Float16*)(sm + ldsoff(PSX, row0 + 0, col)) = pf[nt].x;
            *(_Float16*)(sm + ldsoff(PSX, row0 + 1, col)) = pf[nt].y;
            *(_Float16*)(sm + ldsoff(PSX, row0 + 2, col)) = pf[nt].z;
            *(_Float16*)(sm + ldsoff(PSX, row0 + 3, col)) = pf[nt].w;
        }
    }
    __syncthreads();

    if (act) {
        half4 pa[7];
#pragma unroll
        for (int kt = 0; kt < 7; ++kt)
            pa[kt] = *(const half4*)(sm + ldsoff(PSX, mt * 16 + ml, kt * 16 + gq * 4));
#pragma unroll
        for (int nt = 0; nt < 8; ++nt) {
            f32x4 acc = {0.f, 0.f, 0.f, 0.f};
            const int col = nt * 16 + ml;
#pragma unroll
            for (int kt = 0; kt < 7; ++kt) {
                const int r0 = kt * 16 + gq * 4;
                half4 b = half4{
                    *(const _Float16*)(sm + VSO + ldsoff(PSX, r0 + 0, col)),
                    *(const _Float16*)(sm + VSO + ldsoff(PSX, r0 + 1, col)),
                    *(const _Float16*)(sm + VSO + ldsoff(PSX, r0 + 2, col)),
                    *(const _Float16*)(sm + VSO + ldsoff(PSX, r0 + 3, col))};
                acc = MFMA16(pa[kt], b, acc);
            }
            const int row0 = mt * 16 + gq * 4;
            float* op = obuf + (size_t)t * EN * DD + row0 * DD + col;
            if (row0 + 0 < EN) op[0]       = acc.x;
            if (row0 + 1 < EN) op[DD]      = acc.y;
            if (row0 + 2 < EN) op[2 * DD]  = acc.z;
            if (row0 + 3 < EN) op[3 * DD]  = acc.w;
        }
    }
}

// =====================================================================
// MLP head: block = (64 rows, agent a). Packed W1/W2 frags from global,
// hdn wave-private in LDS (no barriers), fast tanh.
// =====================================================================
#define PSH 8704           // 64*136
#define PSW 17408          // 128*136

__global__ __launch_bounds__(256) void mlp_kernel(
    const float* __restrict__ obuf, const _Float16* __restrict__ wpk,
    const float* __restrict__ B1, const float* __restrict__ B2,
    float* __restrict__ out)
{
    const int a = blockIdx.y;
    const int tid = threadIdx.x;
    const int w = tid >> 6, lane = tid & 63, ml = lane & 15, gq = lane >> 4;
    const int rowbase = blockIdx.x * 64 + w * 16;

    __shared__ __attribute__((aligned(16))) unsigned char sm[PSH * 2];

    const _Float16* w1b = wpk + ((size_t)OFF_MW1 + a * 4096) * 4;
    const _Float16* w2b = wpk + ((size_t)OFF_MW2 + a * 2048) * 4;

    // layer 1: hdn = tanh(O @ W1 + b1) -> LDS f16 (wave-private rows)
    half4 xa[8];
#pragma unroll
    for (int kt = 0; kt < 8; ++kt) {
        float4 f = *reinterpret_cast<const float4*>(
            obuf + (size_t)(rowbase + ml) * 128 + kt * 16 + gq * 4);
        xa[kt] = half4{(_Float16)f.x, (_Float16)f.y, (_Float16)f.z, (_Float16)f.w};
    }
#pragma unroll
    for (int nt = 0; nt < 8; ++nt) {
        const int col = nt * 16 + ml;
        float bv = B1[a * 128 + col];
        f32x4 acc = {bv, bv, bv, bv};
#pragma unroll
        for (int kt = 0; kt < 8; ++kt) {
            half4 b = *(const half4*)(w1b +
                (size_t)(((((kt * 8 + nt) * 4) + gq) * 16 + ml) * 4));
            acc = MFMA16(xa[kt], b, acc);
        }
        const int lr0 = w * 16 + gq * 4;
        *(_Float16*)(sm + ldsoff(PSH, lr0 + 0, col)) = (_Float16)ftanh(acc.x);
        *(_Float16*)(sm + ldsoff(PSH, lr0 + 1, col)) = (_Float16)ftanh(acc.y);
        *(_Float16*)(sm + ldsoff(PSH, lr0 + 2, col)) = (_Float16)ftanh(acc.z);
        *(_Float16*)(sm + ldsoff(PSH, lr0 + 3, col)) = (_Float16)ftanh(acc.w);
    }

    // layer 2: out = hdn @ W2 + b2 (cols 60; packed W2 zero-padded to 64)
    half4 ha[8];
#pragma unroll
    for (int kt = 0; kt < 8; ++kt)
        ha[kt] = *(const half4*)(sm + ldsoff(PSH, w * 16 + ml, kt * 16 + gq * 4));
#pragma unroll
    for (int nt = 0; nt < 4; ++nt) {
        const int o = nt * 16 + ml;
        const bool valid = o < 60;
        float bv = valid ? B2[a * 60 + o] : 0.f;
        f32x4 acc = {bv, bv, bv, bv};
#pragma unroll
        for (int kt = 0; kt < 8; ++kt) {
            half4 b = *(const half4*)(w2b +
                (size_t)(((((kt * 4 + nt) * 4) + gq) * 16 + ml) * 4));
            acc = MFMA16(ha[kt], b, acc);
        }
        if (valid) {
            float* op = out + (size_t)a * 192000 + (size_t)(rowbase + gq * 4) * 60 + o;
            op[0]   = acc.x;
            op[60]  = acc.y;
            op[120] = acc.z;
            op[180] = acc.w;
        }
    }
}

// =====================================================================
extern "C" void kernel_launch(void* const* d_in, const int* in_sizes, int n_in,
                              void* d_out, int out_size, void* d_ws, size_t ws_size,
                              hipStream_t stream)
{
    const float* agent_feature = (const float*)d_in[2];
    const float* map_feature   = (const float*)d_in[3];
    const float* obj_feature   = (const float*)d_in[6];
    const float* aW0 = (const float*)d_in[7];  const float* aB0 = (const float*)d_in[8];
    const float* aW1 = (const float*)d_in[9];  const float* aB1 = (const float*)d_in[10];
    const float* aW2 = (const float*)d_in[11]; const float* aB2 = (const float*)d_in[12];
    const float* mW0 = (const float*)d_in[13]; const float* mB0 = (const float*)d_in[14];
    const float* mW1 = (const float*)d_in[15]; const float* mB1 = (const float*)d_in[16];
    const float* mW2 = (const float*)d_in[17]; const float* mB2 = (const float*)d_in[18];
    const float* oW0 = (const float*)d_in[19]; const float* oB0 = (const float*)d_in[20];
    const float* oW1 = (const float*)d_in[21]; const float* oB1 = (const float*)d_in[22];
    const float* oW2 = (const float*)d_in[23]; const float* oB2 = (const float*)d_in[24];
    const float* Wq = (const float*)d_in[25];
    const float* Wk = (const float*)d_in[26];
    const float* Wv = (const float*)d_in[27];
    const float* mlpW1 = (const float*)d_in[28]; const float* mlpB1 = (const float*)d_in[29];
    const float* mlpW2 = (const float*)d_in[30]; const float* mlpB2 = (const float*)d_in[31];

    float* xbuf = (float*)d_ws;                    // [T,100,128] f32
    float* obuf = xbuf + 409600;                   // [T,100,128] f32
    _Float16* qh = (_Float16*)(obuf + 409600);     // [T,112,128] f16
    _Float16* kh = qh + 458752;
    _Float16* vh = kh + 458752;
    _Float16* wpk = vh + 458752;                   // packed weights

    float* outp = (float*)d_out;

    // ---- pack all weights to f16 fragments (one launch) ----
    PackArgs pa;
    auto seg = [&](int s, const float* src, int C, int VC, int ktc, int ntc, int dsto) {
        pa.src[s] = src; pa.C[s] = C; pa.VC[s] = VC;
        pa.ktc[s] = ktc; pa.ntc[s] = ntc; pa.dsto[s] = dsto;
    };
    seg(0, aW0, 64, 64, 1, 4, OFF_AW);
    seg(1, aW1, 64, 64, 4, 4, OFF_AW + 256);
    seg(2, aW2, 64, 64, 4, 4, OFF_AW + 1280);
    seg(3, mW0, 64, 64, 1, 4, OFF_MW);
    seg(4, mW1, 64, 64, 4, 4, OFF_MW + 256);
    seg(5, mW2, 64, 64, 4, 4, OFF_MW + 1280);
    seg(6, oW0, 64, 64, 1, 4, OFF_OW);
    seg(7, oW1, 64, 64, 4, 4, OFF_OW + 256);
    seg(8, oW2, 64, 64, 4, 4, OFF_OW + 1280);
    seg(9,  Wq, 128, 128, 8, 8, OFF_QKV);
    seg(10, Wk, 128, 128, 8, 8, OFF_QKV + 4096);
    seg(11, Wv, 128, 128, 8, 8, OFF_QKV + 8192);
    for (int a = 0; a < 4; ++a) {
        seg(12 + a, mlpW1 + (size_t)a * 16384, 128, 128, 8, 8, OFF_MW1 + a * 4096);
        seg(16 + a, mlpW2 + (size_t)a * 7680,  60,  60,  8, 4, OFF_MW2 + a * 2048);
    }
    pack_w<<<dim3(16, 20), 256, 0, stream>>>(pa, wpk);

    // ---- merged polyline subgraphs -> x [T, E=100, 128] ----
    SubArgs sa;
    sa.feat[0] = agent_feature; sa.feat[1] = map_feature; sa.feat[2] = obj_feature;
    sa.wp[0] = wpk + OFF_AW * 4; sa.wp[1] = wpk + OFF_MW * 4; sa.wp[2] = wpk + OFF_OW * 4;
    sa.B0[0] = aB0; sa.B0[1] = mB0; sa.B0[2] = oB0;
    sa.W1[0] = aW1; sa.W1[1] = mW1; sa.W1[2] = oW1;
    sa.B1[0] = aB1; sa.B1[1] = mB1; sa.B1[2] = oB1;
    sa.W2[0] = aW2; sa.W2[1] = mW2; sa.W2[2] = oW2;
    sa.B2[0] = aB2; sa.B2[1] = mB2; sa.B2[2] = oB2;
    sa.e_base[0] = 0; sa.e_base[1] = 4; sa.e_base[2] = 68;
    sa.lo[0] = 0; sa.lo[1] = 128; sa.lo[2] = 128 + 2048;
    sa.mtl[0] = 2; sa.mtl[1] = 2; sa.mtl[2] = 1;
    sa.dn[0] = 1; sa.dn[1] = 0; sa.dn[2] = 0;
    subnet_uber<<<dim3(3200), 512, 0, stream>>>(sa, xbuf);

    qkv_kernel<<<dim3(TT, 3), 256, 0, stream>>>(xbuf, wpk + OFF_QKV * 4, qh, kh, vh);
    attn_kernel<<<dim3(TT, 2), 256, 0, stream>>>(qh, kh, vh, obuf);
    mlp_kernel<<<dim3(50, 4), 256, 0, stream>>>(obuf, wpk, mlpB1, mlpB2, outp);
}